// Round 13
// baseline (20749.780 us; speedup 1.0000x reference)
//
#include <hip/hip_runtime.h>
#include <math.h>

// Round 13 (on R12, 20.0 ms): 4 bounded fixes.
//  1. conv3x3 ic-step 8 (half the barriers; ic ascending -> z bit-exact)
//  2. convt oc-tile 128 (halves input re-fetch; decoder tolerance loose)
//  3. VQ parallel f2/dot/argmin (exact numpy op-sequence + first-index semantics)
//  4. dow half-row split (validated in R10)
// Anchors (frozen): fp32 encoder convs, fp32 op-order epilogue, VQ fp32-grid
// emulation, first-index argmin, ws layout (~105 MB).

static constexpr float kBNF = 0.9999950000374997f;

// ---------------------------------------------------------------- conv0: 1->128, 3x3, s1, relu (B=1), fp32
__global__ __launch_bounds__(320) void conv0_k(const float* __restrict__ x,
                                               const float* __restrict__ w,
                                               const float* __restrict__ b,
                                               float* __restrict__ out) {
  const int H = 320, W = 320, OC = 128;
  int oy = blockIdx.x;
  int tx = threadIdx.x;
  __shared__ float in_s[3][W + 2];
  __shared__ float w_s[128 * 9];
  __shared__ float b_s[128];
  for (int e = tx; e < 3 * (W + 2); e += 320) {
    int r = e / (W + 2), c = e % (W + 2);
    int iy = oy + r - 1, ix = c - 1;
    float v = 0.f;
    if (iy >= 0 && iy < H && ix >= 0 && ix < W) v = x[iy * W + ix];
    in_s[r][c] = v;
  }
  for (int e = tx; e < 128 * 9; e += 320) w_s[e] = w[e];
  for (int e = tx; e < 128; e += 320) b_s[e] = b[e];
  __syncthreads();
  float iv[9];
#pragma unroll
  for (int r = 0; r < 3; ++r)
#pragma unroll
    for (int c = 0; c < 3; ++c) iv[r * 3 + c] = in_s[r][tx + c];
  for (int oc = 0; oc < OC; ++oc) {
    float acc = 0.f;
#pragma unroll
    for (int t = 0; t < 9; ++t) acc = fmaf(w_s[oc * 9 + t], iv[t], acc);
    float v32 = __fadd_rn(acc, b_s[oc]);
    v32 = __fmul_rn(v32, kBNF);
    out[(oc * H + oy) * W + tx] = fmaxf(v32, 0.f);
  }
}

// ---------------------------------------------------------------- conv3x3 weight transpose: w2[(ic*9+tap)*OC+oc]
__global__ __launch_bounds__(256) void prep_w3_k(const float* __restrict__ w,
                                                 float* __restrict__ w2,
                                                 int IC, int OC) {
  int i = blockIdx.x * 256 + threadIdx.x;
  int total = IC * OC * 9;
  if (i >= total) return;
  int oc = i % OC;
  int rest = i / OC;
  int tap = rest % 9;
  int ic = rest / 9;
  w2[i] = w[((size_t)oc * IC + ic) * 9 + tap];
}

// ---------------------------------------------------------------- 3x3 conv: ICS=8 (half the barriers), bit-exact order
template <int S, bool RELU, bool HAS_SKIP>
__global__ __launch_bounds__(256) void conv3x3_k(
    const float* __restrict__ in, const float* __restrict__ w2,
    const float* __restrict__ bias, const float* __restrict__ skip,
    float* __restrict__ out, int IC, int IH, int IW, int OC, int OH, int OW) {
  // S=1: in_f[icr][ky][68] plain cols (66 used)
  // S=2: in_f[icr][ky][136]: [0..67]=even cols, [68..135]=odd cols
  __shared__ float in_f[8][3][(S == 1) ? 68 : 136];
  __shared__ float w_f[8][9][64];
  int t = threadIdx.x;
  int ox0 = blockIdx.x * 64;
  int oy = blockIdx.y;
  int oc0 = blockIdx.z * 64;
  int oc4 = (t >> 4) * 4, px4 = (t & 15) * 4;
  float acc[4][4] = {};
  const int NCOL = 64 * S + 2;  // 66 or 130
  const int NIN = 8 * 3 * NCOL;
  for (int ic0 = 0; ic0 < IC; ic0 += 8) {
    __syncthreads();
    for (int e = t; e < NIN; e += 256) {
      int icr = e / (3 * NCOL);
      int rem = e - icr * (3 * NCOL);
      int r = rem / NCOL, c = rem - r * NCOL;
      int iy = oy * S - 1 + r;
      int ix = ox0 * S - 1 + c;
      float v = 0.f;
      if (iy >= 0 && iy < IH && ix >= 0 && ix < IW)
        v = in[((ic0 + icr) * IH + iy) * IW + ix];
      if (S == 1)
        in_f[icr][r][c] = v;
      else
        in_f[icr][r][(c & 1) * 68 + (c >> 1)] = v;
    }
    for (int e = t; e < 8 * 9 * 64; e += 256) {
      int ocr = e & 63;
      int rem = e >> 6;
      int tap = rem % 9, icr = rem / 9;
      w_f[icr][tap][ocr] = w2[((size_t)(ic0 + icr) * 9 + tap) * OC + oc0 + ocr];
    }
    __syncthreads();
#pragma unroll
    for (int icr = 0; icr < 8; ++icr) {
#pragma unroll
      for (int ky = 0; ky < 3; ++ky) {
        float iv[9];
        if (S == 1) {
          float4 va = *reinterpret_cast<const float4*>(&in_f[icr][ky][px4]);
          float2 vb = *reinterpret_cast<const float2*>(&in_f[icr][ky][px4 + 4]);
          iv[0] = va.x; iv[1] = va.y; iv[2] = va.z;
          iv[3] = va.w; iv[4] = vb.x; iv[5] = vb.y;
        } else {
          float4 ve = *reinterpret_cast<const float4*>(&in_f[icr][ky][px4]);
          float se = in_f[icr][ky][px4 + 4];
          float4 vo = *reinterpret_cast<const float4*>(&in_f[icr][ky][68 + px4]);
          iv[0] = ve.x; iv[1] = ve.y; iv[2] = ve.z;
          iv[3] = ve.w; iv[4] = se;
          iv[5] = vo.x; iv[6] = vo.y; iv[7] = vo.z; iv[8] = vo.w;
        }
#pragma unroll
        for (int kx = 0; kx < 3; ++kx) {
          float4 wv = *reinterpret_cast<const float4*>(&w_f[icr][ky * 3 + kx][oc4]);
          const float* wp = (const float*)&wv;
#pragma unroll
          for (int p = 0; p < 4; ++p) {
            float ivv;
            if (S == 1) {
              ivv = iv[p + kx];
            } else {
              ivv = (kx == 0) ? iv[p] : (kx == 1) ? iv[5 + p] : iv[p + 1];
            }
#pragma unroll
            for (int o = 0; o < 4; ++o)
              acc[o][p] = fmaf(wp[o], ivv, acc[o][p]);
          }
        }
      }
    }
  }
  int opx = ox0 + px4;
  if (opx < OW) {
#pragma unroll
    for (int o = 0; o < 4; ++o) {
      int oc = oc0 + oc4 + o;
      float bv = bias[oc];
      size_t base = ((size_t)oc * OH + oy) * OW + opx;
      float4 rv;
      float* rp = (float*)&rv;
#pragma unroll
      for (int p = 0; p < 4; ++p) {
        float v32 = __fadd_rn(acc[o][p], bv);
        v32 = __fmul_rn(v32, kBNF);
        if (HAS_SKIP) v32 = __fadd_rn(v32, skip[base + p]);
        if (RELU) v32 = fmaxf(v32, 0.f);
        rp[p] = v32;
      }
      *reinterpret_cast<float4*>(&out[base]) = rv;
    }
  }
}

// ---------------------------------------------------------------- 1x1 conv, fp32 acc (R12)
template <int S, bool RELU>
__global__ __launch_bounds__(256) void conv1x1_k(
    const float* __restrict__ in, const float* __restrict__ w,
    const float* __restrict__ bias, float* __restrict__ out,
    int IC, int IH, int IW, int OC, int OH, int OW) {
  __shared__ float in_s[16][64];
  __shared__ float w_s[16][64];
  const int P = OH * OW;
  int t = threadIdx.x;
  int p0 = blockIdx.x * 64;
  int oc0 = blockIdx.y * 64;
  int oc4 = (t >> 4) * 4, px4 = (t & 15) * 4;
  float acc[4][4] = {};
  for (int ic0 = 0; ic0 < IC; ic0 += 16) {
    __syncthreads();
    {
      int e = t;
#pragma unroll
      for (int k = 0; k < 4; ++k, e += 256) {
        int icr = e >> 6, pxr = e & 63;
        int p = p0 + pxr;
        float v = 0.f;
        if (p < P) {
          int oy = p / OW, ox = p % OW;
          v = in[((ic0 + icr) * IH + oy * S) * IW + ox * S];
        }
        in_s[icr][pxr] = v;
      }
      e = t;
#pragma unroll
      for (int k = 0; k < 4; ++k, e += 256) {
        int icr = e >> 6, ocr = e & 63;
        w_s[icr][ocr] = w[(oc0 + ocr) * IC + ic0 + icr];
      }
    }
    __syncthreads();
#pragma unroll
    for (int icr = 0; icr < 16; ++icr) {
      float4 iv = *reinterpret_cast<const float4*>(&in_s[icr][px4]);
      float4 wv = *reinterpret_cast<const float4*>(&w_s[icr][oc4]);
      const float* ip = (const float*)&iv;
      const float* wp = (const float*)&wv;
#pragma unroll
      for (int o = 0; o < 4; ++o)
#pragma unroll
        for (int p = 0; p < 4; ++p)
          acc[o][p] = fmaf(wp[o], ip[p], acc[o][p]);
    }
  }
  int p = p0 + px4;
  if (p < P) {
    int oy = p / OW, ox = p % OW;
#pragma unroll
    for (int o = 0; o < 4; ++o) {
      int oc = oc0 + oc4 + o;
      float bv = bias[oc];
      float4 rv;
      float* rp = (float*)&rv;
#pragma unroll
      for (int pp = 0; pp < 4; ++pp) {
        float v32 = __fadd_rn(acc[o][pp], bv);
        v32 = __fmul_rn(v32, kBNF);
        if (RELU) v32 = fmaxf(v32, 0.f);
        rp[pp] = v32;
      }
      *reinterpret_cast<float4*>(&out[((size_t)oc * OH + oy) * OW + ox]) = rv;
    }
  }
}

// ---------------------------------------------------------------- ConvT weight transpose: w2[kyb][ic][ty][kx][OC]
__global__ __launch_bounds__(256) void prep_w2_k(const float* __restrict__ w,
                                                 float* __restrict__ w2,
                                                 int IC, int OC) {
  int i = blockIdx.x * 256 + threadIdx.x;
  int total = IC * OC * 16;
  if (i >= total) return;
  int oc = i % OC;
  int r = i / OC;
  int kx = r & 3; r >>= 2;
  int ty = r & 1; r >>= 1;
  int ic = r % IC;
  int kyb = r / IC;
  int ky = kyb + 2 * ty;
  w2[i] = w[((size_t)ic * OC + oc) * 16 + ky * 4 + kx];
}

// ---------------------------------------------------------------- ConvTranspose2d k4 s2 p1, relu, ICS=8, OCT=128
__global__ __launch_bounds__(256) void convt_k(
    const float* __restrict__ in, const float* __restrict__ w2,
    const float* __restrict__ bias, float* __restrict__ out,
    int IC, int IH, int IW, int OC, int OH, int OW) {
  __shared__ float in_s[8][2][34];
  __shared__ float w_s[8][2][4][128];   // 32 KB
  int t = threadIdx.x;
  int ox0 = blockIdx.x * 64;
  int oy = blockIdx.y;
  int oc0 = blockIdx.z * 128;
  int oc8 = (t >> 4) * 8, px4 = (t & 15) * 4;
  int h = px4 >> 1;
  int kyb = (oy & 1) ? 0 : 1;
  int c0 = ox0 >> 1;
  const float* w2b = w2 + (size_t)kyb * IC * 8 * OC;  // [ic][ty][kx][OC]
  float acc[8][4] = {};
  for (int ic0 = 0; ic0 < IC; ic0 += 8) {
    __syncthreads();
    for (int e = t; e < 8 * 2 * 34; e += 256) {
      int icr = e / 68;
      int rem = e - icr * 68;
      int ty = rem / 34, cc = rem - ty * 34;
      int ky = kyb + 2 * ty;
      int iy = (oy + 1 - ky) >> 1;
      int ix = c0 - 1 + cc;
      float v = 0.f;
      if (iy >= 0 && iy < IH && ix >= 0 && ix < IW)
        v = in[((ic0 + icr) * IH + iy) * IW + ix];
      in_s[icr][ty][cc] = v;
    }
    {
      int e = t;
#pragma unroll
      for (int k = 0; k < 32; ++k, e += 256) {  // 8*2*4*128 = 8192
        int ocr = e & 127;
        int rem = e >> 7;
        int kx = rem & 3;
        int ty = (rem >> 2) & 1;
        int icr = rem >> 3;
        w_s[icr][ty][kx][ocr] =
            w2b[((((size_t)(ic0 + icr)) * 2 + ty) * 4 + kx) * OC + oc0 + ocr];
      }
    }
    __syncthreads();
#pragma unroll
    for (int icr = 0; icr < 8; ++icr) {
      float cA[2][4];
#pragma unroll
      for (int ty = 0; ty < 2; ++ty) {
        float2 a = *reinterpret_cast<const float2*>(&in_s[icr][ty][h]);
        float2 b2 = *reinterpret_cast<const float2*>(&in_s[icr][ty][h + 2]);
        cA[ty][0] = a.x; cA[ty][1] = a.y; cA[ty][2] = b2.x; cA[ty][3] = b2.y;
      }
      // per kx: applies to 2 of 4 p's, input col index into cA:
      // kx0: (p1,c2),(p3,c3); kx1: (p0,c1),(p2,c2); kx2: (p1,c1),(p3,c2); kx3: (p0,c0),(p2,c1)
      const int PT[4][2] = {{1, 3}, {0, 2}, {1, 3}, {0, 2}};
      const int CT[4][2] = {{2, 3}, {1, 2}, {1, 2}, {0, 1}};
#pragma unroll
      for (int ty = 0; ty < 2; ++ty) {
#pragma unroll
        for (int kx = 0; kx < 4; ++kx) {
          float4 w0 = *reinterpret_cast<const float4*>(&w_s[icr][ty][kx][oc8]);
          float4 w1 = *reinterpret_cast<const float4*>(&w_s[icr][ty][kx][oc8 + 4]);
          const float* wr0 = (const float*)&w0;
          const float* wr1 = (const float*)&w1;
#pragma unroll
          for (int q = 0; q < 2; ++q) {
            int p = PT[kx][q];
            float s = cA[ty][CT[kx][q]];
#pragma unroll
            for (int o = 0; o < 4; ++o) {
              acc[o][p] = fmaf(wr0[o], s, acc[o][p]);
              acc[o + 4][p] = fmaf(wr1[o], s, acc[o + 4][p]);
            }
          }
        }
      }
    }
  }
  int opx = ox0 + px4;
  if (opx < OW) {
#pragma unroll
    for (int o = 0; o < 8; ++o) {
      int oc = oc0 + oc8 + o;
      float bv = bias[oc];
      float4 rv;
      float* rp = (float*)&rv;
#pragma unroll
      for (int p = 0; p < 4; ++p) {
        float v = (acc[o][p] + bv) * kBNF;
        rp[p] = fmaxf(v, 0.f);
      }
      *reinterpret_cast<float4*>(&out[((size_t)oc * OH + oy) * OW + opx]) = rv;
    }
  }
}

// ---------------------------------------------------------------- final 3x3 conv 128->1 + sigmoid, half-rows (R10)
__global__ __launch_bounds__(192) void dow_k(const float* __restrict__ in,
                                             const float* __restrict__ w,
                                             const float* __restrict__ bias,
                                             float* __restrict__ out) {
  const int H = 320, W = 320, IC = 128;
  int oy = blockIdx.y;
  int ox0 = blockIdx.x * 160;
  int tx = threadIdx.x;
  __shared__ float in_s[4][3][164];
  __shared__ float w_s[IC * 9];
  for (int e = tx; e < IC * 9; e += 192) w_s[e] = w[e];
  float acc = 0.f;
  for (int ic0 = 0; ic0 < IC; ic0 += 4) {
    __syncthreads();
    for (int e = tx; e < 4 * 3 * 162; e += 192) {
      int icr = e / 486;
      int rem = e - icr * 486;
      int r = rem / 162, c = rem - r * 162;
      int iy = oy + r - 1, ix = ox0 + c - 1;
      float v = 0.f;
      if (iy >= 0 && iy < H && ix >= 0 && ix < W)
        v = in[((ic0 + icr) * H + iy) * W + ix];
      in_s[icr][r][c] = v;
    }
    __syncthreads();
    if (tx < 160) {
#pragma unroll
      for (int icr = 0; icr < 4; ++icr)
#pragma unroll
        for (int r = 0; r < 3; ++r)
#pragma unroll
          for (int c = 0; c < 3; ++c)
            acc = fmaf(w_s[(ic0 + icr) * 9 + r * 3 + c], in_s[icr][r][tx + c], acc);
    }
  }
  if (tx < 160) {
    acc += bias[0];
    out[oy * W + ox0 + tx] = 1.f / (1.f + expf(-acc));
  }
}

// ---------------------------------------------------------------- codebook sq-norms: numpy-pairwise fp32
__global__ __launch_bounds__(256) void cbprep_np(const float* __restrict__ cb,
                                                 float* __restrict__ c2f) {
  int e = blockIdx.x, t = threadIdx.x;
  __shared__ float a[256];
  a[t] = cb[e * 256 + t];
  __syncthreads();
  if (t == 0) {
    float tot = 0.f;
    for (int h = 0; h < 2; ++h) {
      const float* p = a + h * 128;
      float r[8];
#pragma unroll
      for (int j = 0; j < 8; ++j) r[j] = __fmul_rn(p[j], p[j]);
      for (int i = 8; i < 128; i += 8)
#pragma unroll
        for (int j = 0; j < 8; ++j) r[j] = __fadd_rn(r[j], __fmul_rn(p[i + j], p[i + j]));
      float s = __fadd_rn(__fadd_rn(__fadd_rn(r[0], r[1]), __fadd_rn(r[2], r[3])),
                          __fadd_rn(__fadd_rn(r[4], r[5]), __fadd_rn(r[6], r[7])));
      tot = (h == 0) ? s : __fadd_rn(tot, s);
    }
    c2f[e] = tot;
  }
}

// ---------------------------------------------------------------- VQ: parallel f2 / float4 dot / tree argmin
// Identical arithmetic to the serial version: numpy-pairwise f2 op sequence,
// fp64 dot in ascending d order, fp32 dist grid, first-index argmin.
__global__ __launch_bounds__(256) void vq_ref_k(const float* __restrict__ z,
                                                const float* __restrict__ cb,
                                                const float* __restrict__ c2f,
                                                float* __restrict__ zq_out,
                                                float* __restrict__ idx_out) {
  int row = blockIdx.x;
  int t = threadIdx.x;
  __shared__ float f[256];
  __shared__ float dist[1024];
  __shared__ float rr[2][8];
  __shared__ float f2s;
  __shared__ float rv_s[256];
  __shared__ int ri_s[256];
  __shared__ int bestIdx;
  f[t] = z[(size_t)row * 256 + t];
  __syncthreads();
  // parallel f2: 16 threads compute numpy's 8 stride-8 partials per 128-half
  if (t < 16) {
    int hh = t >> 3, j = t & 7;
    const float* p = f + hh * 128;
    float r = __fmul_rn(p[j], p[j]);
    for (int i = 8; i < 128; i += 8) r = __fadd_rn(r, __fmul_rn(p[i + j], p[i + j]));
    rr[hh][j] = r;
  }
  __syncthreads();
  if (t == 0) {
    float s0 = __fadd_rn(__fadd_rn(__fadd_rn(rr[0][0], rr[0][1]), __fadd_rn(rr[0][2], rr[0][3])),
                         __fadd_rn(__fadd_rn(rr[0][4], rr[0][5]), __fadd_rn(rr[0][6], rr[0][7])));
    float s1 = __fadd_rn(__fadd_rn(__fadd_rn(rr[1][0], rr[1][1]), __fadd_rn(rr[1][2], rr[1][3])),
                         __fadd_rn(__fadd_rn(rr[1][4], rr[1][5]), __fadd_rn(rr[1][6], rr[1][7])));
    f2s = __fadd_rn(s0, s1);
  }
  __syncthreads();
  float f2 = f2s;
  for (int e = t; e < 1024; e += 256) {
    const float4* cbe = reinterpret_cast<const float4*>(cb + (size_t)e * 256);
    double dot = 0.0;
    for (int d = 0; d < 64; ++d) {
      float4 c4 = cbe[d];
      float4 f4 = *reinterpret_cast<const float4*>(&f[d * 4]);
      dot = fma((double)f4.x, (double)c4.x, dot);
      dot = fma((double)f4.y, (double)c4.y, dot);
      dot = fma((double)f4.z, (double)c4.z, dot);
      dot = fma((double)f4.w, (double)c4.w, dot);
    }
    float C = __fmul_rn(2.f, (float)dot);
    dist[e] = __fsub_rn(__fadd_rn(f2, c2f[e]), C);
  }
  __syncthreads();
  // first-index argmin: per-thread ascending scan, then tree reduce (lower index wins ties)
  float bv = dist[t];
  int bi = t;
  for (int e = t + 256; e < 1024; e += 256) {
    float v = dist[e];
    if (v < bv) { bv = v; bi = e; }   // ascending e: strict < keeps lowest index
  }
  rv_s[t] = bv;
  ri_s[t] = bi;
  __syncthreads();
  for (int s = 128; s > 0; s >>= 1) {
    if (t < s) {
      float v2 = rv_s[t + s];
      int i2 = ri_s[t + s];
      if (v2 < rv_s[t] || (v2 == rv_s[t] && i2 < ri_s[t])) { rv_s[t] = v2; ri_s[t] = i2; }
    }
    __syncthreads();
  }
  if (t == 0) {
    bestIdx = ri_s[0];
    idx_out[row] = (float)ri_s[0];
  }
  __syncthreads();
  zq_out[(size_t)row * 256 + t] = cb[(size_t)bestIdx * 256 + t];
}

// ================================================================ host
extern "C" void kernel_launch(void* const* d_in, const int* in_sizes, int n_in,
                              void* d_out, int out_size, void* d_ws, size_t ws_size,
                              hipStream_t stream) {
  const float* x = (const float*)d_in[0];
  const float* w0 = (const float*)d_in[1];
  const float* b0 = (const float*)d_in[2];
  const float* a_c1w = (const float*)d_in[3];
  const float* a_c1b = (const float*)d_in[4];
  const float* a_c2w = (const float*)d_in[5];
  const float* a_c2b = (const float*)d_in[6];
  const float* a_scw = (const float*)d_in[7];
  const float* a_scb = (const float*)d_in[8];
  const float* b_c1w = (const float*)d_in[9];
  const float* b_c1b = (const float*)d_in[10];
  const float* b_c2w = (const float*)d_in[11];
  const float* b_c2b = (const float*)d_in[12];
  const float* b_scw = (const float*)d_in[13];
  const float* b_scb = (const float*)d_in[14];
  const float* ew = (const float*)d_in[15];
  const float* eb = (const float*)d_in[16];
  const float* cb = (const float*)d_in[17];
  const float* d0w = (const float*)d_in[18];
  const float* d0b = (const float*)d_in[19];
  const float* dt1w = (const float*)d_in[20];
  const float* dt1b = (const float*)d_in[21];
  const float* dt2w = (const float*)d_in[22];
  const float* dt2b = (const float*)d_in[23];
  const float* doww = (const float*)d_in[24];
  const float* dob = (const float*)d_in[25];

  // ws (floats): A 13.1M | B 6.55M | C 6.55M | c2f 1024  ~= 105 MB (unchanged)
  float* ws = (float*)d_ws;
  float* A = ws;
  float* Bf = ws + 13107200;
  float* Cf = ws + 19660800;
  float* c2f = ws + 26214400;
  float* w2dt1 = A;              // dead region during decoder
  float* w2dt2 = Bf + 3400000;   // past g0's 3.28M floats
  // conv3x3 transposed weights (dead-region placements, audited R12)
  float* w3_ac1 = Cf;            // 294,912 f
  float* w3_ac2 = A + 6600000;   // 589,824 f
  float* w3_bc1 = Bf + 3300000;  // 1,179,648 f
  float* w3_bc2 = A + 3300000;   // 2,359,296 f

  float* outf = (float*)d_out;
  float* recon = outf;
  float* zq = outf + 409600;
  float* idxo = zq + 6553600;

  cbprep_np<<<1024, 256, 0, stream>>>(cb, c2f);

  for (int b = 0; b < 4; ++b) {
    const float* xb = x + (size_t)b * 102400;
    float* zqb = zq + (size_t)b * 1638400;
    float* idxb = idxo + (size_t)b * 6400;
    float* reconb = recon + (size_t)b * 102400;

    // encoder (fp32; ic ascending + same inner order -> z bit-identical)
    conv0_k<<<320, 320, 0, stream>>>(xb, w0, b0, A);
    prep_w3_k<<<1152, 256, 0, stream>>>(a_c1w, w3_ac1, 128, 256);
    conv3x3_k<2, true, false><<<dim3(3, 160, 4), 256, 0, stream>>>(
        A, w3_ac1, a_c1b, nullptr, Bf, 128, 320, 320, 256, 160, 160);
    conv1x1_k<2, false><<<dim3(400, 4), 256, 0, stream>>>(
        A, a_scw, a_scb, Cf, 128, 320, 320, 256, 160, 160);
    prep_w3_k<<<2304, 256, 0, stream>>>(a_c2w, w3_ac2, 256, 256);
    conv3x3_k<1, true, true><<<dim3(3, 160, 4), 256, 0, stream>>>(
        Bf, w3_ac2, a_c2b, Cf, A, 256, 160, 160, 256, 160, 160);
    prep_w3_k<<<4608, 256, 0, stream>>>(b_c1w, w3_bc1, 256, 512);
    conv3x3_k<2, true, false><<<dim3(2, 80, 8), 256, 0, stream>>>(
        A, w3_bc1, b_c1b, nullptr, Bf, 256, 160, 160, 512, 80, 80);
    conv1x1_k<2, false><<<dim3(100, 8), 256, 0, stream>>>(
        A, b_scw, b_scb, Cf, 256, 160, 160, 512, 80, 80);
    prep_w3_k<<<9216, 256, 0, stream>>>(b_c2w, w3_bc2, 512, 512);
    conv3x3_k<1, true, true><<<dim3(2, 80, 8), 256, 0, stream>>>(
        Bf, w3_bc2, b_c2b, Cf, A, 512, 80, 80, 512, 80, 80);
    conv1x1_k<1, false><<<dim3(100, 4), 256, 0, stream>>>(
        A, ew, eb, Cf, 512, 80, 80, 256, 80, 80);
    // VQ (parallelized, arithmetic identical)
    vq_ref_k<<<6400, 256, 0, stream>>>(Cf, cb, c2f, zqb, idxb);
    // decoder
    prep_w2_k<<<8192, 256, 0, stream>>>(dt1w, w2dt1, 512, 256);
    prep_w2_k<<<2048, 256, 0, stream>>>(dt2w, w2dt2, 256, 128);
    conv1x1_k<1, true><<<dim3(100, 8), 256, 0, stream>>>(
        zqb, d0w, d0b, Bf, 256, 80, 80, 512, 80, 80);
    convt_k<<<dim3(3, 160, 2), 256, 0, stream>>>(
        Bf, w2dt1, dt1b, Cf, 512, 80, 80, 256, 160, 160);
    convt_k<<<dim3(5, 320, 1), 256, 0, stream>>>(
        Cf, w2dt2, dt2b, A, 256, 160, 160, 128, 320, 320);
    dow_k<<<dim3(2, 320), 192, 0, stream>>>(A, doww, dob, reconb);
  }
}

// Round 14
// 15999.359 us; speedup vs baseline: 1.2969x; 1.2969x over previous
//
#include <hip/hip_runtime.h>
#include <hip/hip_bf16.h>
#include <math.h>

// Round 14: decoder ConvT -> bf16 MFMA implicit GEMM (mfma_f32_16x16x32_bf16).
// Encoder/VQ anchors untouched (fp32 convs, fp32-grid VQ emulation, first-index
// argmin). conv3x3 = R13 ICS8 (measured best). dow = R9. VQ = R13 parallel.
// ConvT tiling: block 256 = 4 waves; wave = 16oc x 32px (1 even + 1 odd n-tile);
// grid (OW/32, OH, OC/64). A-frag from prepped global bf16 (lane-linear),
// B-frag from transposed bf16 LDS [ty][ix 18][icpad 40], D layout per m89.

static constexpr float kBNF = 0.9999950000374997f;

typedef short short8 __attribute__((ext_vector_type(8)));
typedef float f32x4 __attribute__((ext_vector_type(4)));

// ---------------------------------------------------------------- conv0: 1->128, 3x3, s1, relu (B=1), fp32
__global__ __launch_bounds__(320) void conv0_k(const float* __restrict__ x,
                                               const float* __restrict__ w,
                                               const float* __restrict__ b,
                                               float* __restrict__ out) {
  const int H = 320, W = 320, OC = 128;
  int oy = blockIdx.x;
  int tx = threadIdx.x;
  __shared__ float in_s[3][W + 2];
  __shared__ float w_s[128 * 9];
  __shared__ float b_s[128];
  for (int e = tx; e < 3 * (W + 2); e += 320) {
    int r = e / (W + 2), c = e % (W + 2);
    int iy = oy + r - 1, ix = c - 1;
    float v = 0.f;
    if (iy >= 0 && iy < H && ix >= 0 && ix < W) v = x[iy * W + ix];
    in_s[r][c] = v;
  }
  for (int e = tx; e < 128 * 9; e += 320) w_s[e] = w[e];
  for (int e = tx; e < 128; e += 320) b_s[e] = b[e];
  __syncthreads();
  float iv[9];
#pragma unroll
  for (int r = 0; r < 3; ++r)
#pragma unroll
    for (int c = 0; c < 3; ++c) iv[r * 3 + c] = in_s[r][tx + c];
  for (int oc = 0; oc < OC; ++oc) {
    float acc = 0.f;
#pragma unroll
    for (int t = 0; t < 9; ++t) acc = fmaf(w_s[oc * 9 + t], iv[t], acc);
    float v32 = __fadd_rn(acc, b_s[oc]);
    v32 = __fmul_rn(v32, kBNF);
    out[(oc * H + oy) * W + tx] = fmaxf(v32, 0.f);
  }
}

// ---------------------------------------------------------------- conv3x3 weight transpose: w2[(ic*9+tap)*OC+oc]
__global__ __launch_bounds__(256) void prep_w3_k(const float* __restrict__ w,
                                                 float* __restrict__ w2,
                                                 int IC, int OC) {
  int i = blockIdx.x * 256 + threadIdx.x;
  int total = IC * OC * 9;
  if (i >= total) return;
  int oc = i % OC;
  int rest = i / OC;
  int tap = rest % 9;
  int ic = rest / 9;
  w2[i] = w[((size_t)oc * IC + ic) * 9 + tap];
}

// ---------------------------------------------------------------- 3x3 conv: ICS=8 (R13, bit-exact order)
template <int S, bool RELU, bool HAS_SKIP>
__global__ __launch_bounds__(256) void conv3x3_k(
    const float* __restrict__ in, const float* __restrict__ w2,
    const float* __restrict__ bias, const float* __restrict__ skip,
    float* __restrict__ out, int IC, int IH, int IW, int OC, int OH, int OW) {
  __shared__ float in_f[8][3][(S == 1) ? 68 : 136];
  __shared__ float w_f[8][9][64];
  int t = threadIdx.x;
  int ox0 = blockIdx.x * 64;
  int oy = blockIdx.y;
  int oc0 = blockIdx.z * 64;
  int oc4 = (t >> 4) * 4, px4 = (t & 15) * 4;
  float acc[4][4] = {};
  const int NCOL = 64 * S + 2;
  const int NIN = 8 * 3 * NCOL;
  for (int ic0 = 0; ic0 < IC; ic0 += 8) {
    __syncthreads();
    for (int e = t; e < NIN; e += 256) {
      int icr = e / (3 * NCOL);
      int rem = e - icr * (3 * NCOL);
      int r = rem / NCOL, c = rem - r * NCOL;
      int iy = oy * S - 1 + r;
      int ix = ox0 * S - 1 + c;
      float v = 0.f;
      if (iy >= 0 && iy < IH && ix >= 0 && ix < IW)
        v = in[((ic0 + icr) * IH + iy) * IW + ix];
      if (S == 1)
        in_f[icr][r][c] = v;
      else
        in_f[icr][r][(c & 1) * 68 + (c >> 1)] = v;
    }
    for (int e = t; e < 8 * 9 * 64; e += 256) {
      int ocr = e & 63;
      int rem = e >> 6;
      int tap = rem % 9, icr = rem / 9;
      w_f[icr][tap][ocr] = w2[((size_t)(ic0 + icr) * 9 + tap) * OC + oc0 + ocr];
    }
    __syncthreads();
#pragma unroll
    for (int icr = 0; icr < 8; ++icr) {
#pragma unroll
      for (int ky = 0; ky < 3; ++ky) {
        float iv[9];
        if (S == 1) {
          float4 va = *reinterpret_cast<const float4*>(&in_f[icr][ky][px4]);
          float2 vb = *reinterpret_cast<const float2*>(&in_f[icr][ky][px4 + 4]);
          iv[0] = va.x; iv[1] = va.y; iv[2] = va.z;
          iv[3] = va.w; iv[4] = vb.x; iv[5] = vb.y;
        } else {
          float4 ve = *reinterpret_cast<const float4*>(&in_f[icr][ky][px4]);
          float se = in_f[icr][ky][px4 + 4];
          float4 vo = *reinterpret_cast<const float4*>(&in_f[icr][ky][68 + px4]);
          iv[0] = ve.x; iv[1] = ve.y; iv[2] = ve.z;
          iv[3] = ve.w; iv[4] = se;
          iv[5] = vo.x; iv[6] = vo.y; iv[7] = vo.z; iv[8] = vo.w;
        }
#pragma unroll
        for (int kx = 0; kx < 3; ++kx) {
          float4 wv = *reinterpret_cast<const float4*>(&w_f[icr][ky * 3 + kx][oc4]);
          const float* wp = (const float*)&wv;
#pragma unroll
          for (int p = 0; p < 4; ++p) {
            float ivv;
            if (S == 1) {
              ivv = iv[p + kx];
            } else {
              ivv = (kx == 0) ? iv[p] : (kx == 1) ? iv[5 + p] : iv[p + 1];
            }
#pragma unroll
            for (int o = 0; o < 4; ++o)
              acc[o][p] = fmaf(wp[o], ivv, acc[o][p]);
          }
        }
      }
    }
  }
  int opx = ox0 + px4;
  if (opx < OW) {
#pragma unroll
    for (int o = 0; o < 4; ++o) {
      int oc = oc0 + oc4 + o;
      float bv = bias[oc];
      size_t base = ((size_t)oc * OH + oy) * OW + opx;
      float4 rv;
      float* rp = (float*)&rv;
#pragma unroll
      for (int p = 0; p < 4; ++p) {
        float v32 = __fadd_rn(acc[o][p], bv);
        v32 = __fmul_rn(v32, kBNF);
        if (HAS_SKIP) v32 = __fadd_rn(v32, skip[base + p]);
        if (RELU) v32 = fmaxf(v32, 0.f);
        rp[p] = v32;
      }
      *reinterpret_cast<float4*>(&out[base]) = rv;
    }
  }
}

// ---------------------------------------------------------------- 1x1 conv, fp32 acc
template <int S, bool RELU>
__global__ __launch_bounds__(256) void conv1x1_k(
    const float* __restrict__ in, const float* __restrict__ w,
    const float* __restrict__ bias, float* __restrict__ out,
    int IC, int IH, int IW, int OC, int OH, int OW) {
  __shared__ float in_s[16][64];
  __shared__ float w_s[16][64];
  const int P = OH * OW;
  int t = threadIdx.x;
  int p0 = blockIdx.x * 64;
  int oc0 = blockIdx.y * 64;
  int oc4 = (t >> 4) * 4, px4 = (t & 15) * 4;
  float acc[4][4] = {};
  for (int ic0 = 0; ic0 < IC; ic0 += 16) {
    __syncthreads();
    {
      int e = t;
#pragma unroll
      for (int k = 0; k < 4; ++k, e += 256) {
        int icr = e >> 6, pxr = e & 63;
        int p = p0 + pxr;
        float v = 0.f;
        if (p < P) {
          int oy = p / OW, ox = p % OW;
          v = in[((ic0 + icr) * IH + oy * S) * IW + ox * S];
        }
        in_s[icr][pxr] = v;
      }
      e = t;
#pragma unroll
      for (int k = 0; k < 4; ++k, e += 256) {
        int icr = e >> 6, ocr = e & 63;
        w_s[icr][ocr] = w[(oc0 + ocr) * IC + ic0 + icr];
      }
    }
    __syncthreads();
#pragma unroll
    for (int icr = 0; icr < 16; ++icr) {
      float4 iv = *reinterpret_cast<const float4*>(&in_s[icr][px4]);
      float4 wv = *reinterpret_cast<const float4*>(&w_s[icr][oc4]);
      const float* ip = (const float*)&iv;
      const float* wp = (const float*)&wv;
#pragma unroll
      for (int o = 0; o < 4; ++o)
#pragma unroll
        for (int p = 0; p < 4; ++p)
          acc[o][p] = fmaf(wp[o], ip[p], acc[o][p]);
    }
  }
  int p = p0 + px4;
  if (p < P) {
    int oy = p / OW, ox = p % OW;
#pragma unroll
    for (int o = 0; o < 4; ++o) {
      int oc = oc0 + oc4 + o;
      float bv = bias[oc];
      float4 rv;
      float* rp = (float*)&rv;
#pragma unroll
      for (int pp = 0; pp < 4; ++pp) {
        float v32 = __fadd_rn(acc[o][pp], bv);
        v32 = __fmul_rn(v32, kBNF);
        if (RELU) v32 = fmaxf(v32, 0.f);
        rp[pp] = v32;
      }
      *reinterpret_cast<float4*>(&out[((size_t)oc * OH + oy) * OW + ox]) = rv;
    }
  }
}

// ---------------------------------------------------------------- ConvT weight prep -> bf16 A-fragments
// wb[((cfg*(OC/16) + ocT)*(IC/32) + kT)*512 + lane*8 + e], cfg=(kyb*2+ty)*4+kx
// frag element (m,k): lane = m + 16*(k>>3), e = k&7; value = W[ic][oc][ky][kx], ky=kyb+2ty
__global__ __launch_bounds__(256) void prep_wb_k(const float* __restrict__ w,
                                                 __hip_bfloat16* __restrict__ wb,
                                                 int IC, int OC) {
  int i = blockIdx.x * 256 + threadIdx.x;
  int total = 16 * IC * OC;
  if (i >= total) return;
  int per_cfg = IC * OC;
  int cfg = i / per_cfg;
  int r = i - cfg * per_cfg;
  int ktiles = IC >> 5;
  int ocT = r / (ktiles * 512);
  int r2 = r - ocT * (ktiles * 512);
  int kT = r2 >> 9;
  int f = r2 & 511;
  int lane = f >> 3, e = f & 7;
  int m = lane & 15, kk = ((lane >> 4) << 3) + e;
  int oc = ocT * 16 + m, ic = kT * 32 + kk;
  int kyb = cfg >> 3, ty = (cfg >> 2) & 1, kx = cfg & 3;
  int ky = kyb + 2 * ty;
  wb[i] = __float2bfloat16(w[((size_t)ic * OC + oc) * 16 + ky * 4 + kx]);
}

// ---------------------------------------------------------------- ConvT k4 s2 p1 via MFMA bf16
// block 256 = 4 waves; wave: 16oc x 32px (even tile ox0+2n, odd tile ox0+1+2n)
__global__ __launch_bounds__(256) void convt_mfma_k(
    const float* __restrict__ in, const __hip_bfloat16* __restrict__ wb,
    const float* __restrict__ bias, float* __restrict__ out,
    int IC, int IH, int IW, int OC, int OH, int OW) {
  __shared__ __align__(16) __hip_bfloat16 lds[2 * 18 * 40];
  int t = threadIdx.x;
  int wv = t >> 6, l = t & 63;
  int ox0 = blockIdx.x * 32;
  int oy = blockIdx.y;
  int oc0w = blockIdx.z * 64 + wv * 16;
  int kyb = (oy & 1) ? 0 : 1;
  int hb = ox0 >> 1;
  // iy per ty (ky = kyb + 2*ty); zero-fill out-of-range
  int iy0n = oy + 1 - kyb;
  int iy0 = iy0n >> 1;
  bool ok0 = (iy0 < IH);                       // iy0n >= 0 always
  int iy1n = oy + 1 - kyb - 2;
  int iy1 = iy1n >> 1;
  bool ok1 = (iy1n >= 0) && (iy1 < IH);
  f32x4 accE = {0.f, 0.f, 0.f, 0.f};
  f32x4 accO = {0.f, 0.f, 0.f, 0.f};
  const int ktiles = IC >> 5;
  int n = l & 15, koff = (l >> 4) * 8;
  const short8* wb8 = reinterpret_cast<const short8*>(wb);
  int ocT = oc0w >> 4;
  const int OCt = OC >> 4;
  for (int kT = 0; kT < ktiles; ++kT) {
    __syncthreads();
    for (int e = t; e < 1152; e += 256) {
      int ic = e / 36;
      int r = e - ic * 36;
      int ty = r / 18, xi = r - ty * 18;
      int ix = hb - 1 + xi;
      int iy = ty ? iy1 : iy0;
      bool ok = ty ? ok1 : ok0;
      float v = 0.f;
      if (ok && ix >= 0 && ix < IW)
        v = in[((size_t)(kT * 32 + ic) * IH + iy) * IW + ix];
      lds[(ty * 18 + xi) * 40 + ic] = __float2bfloat16(v);
    }
    __syncthreads();
#pragma unroll
    for (int ty = 0; ty < 2; ++ty) {
      // A-frags for this ty: kx 0..3
      short8 A0 = wb8[((((kyb * 2 + ty) * 4 + 0) * OCt + ocT) * ktiles + kT) * 64 + l];
      short8 A1 = wb8[((((kyb * 2 + ty) * 4 + 1) * OCt + ocT) * ktiles + kT) * 64 + l];
      short8 A2 = wb8[((((kyb * 2 + ty) * 4 + 2) * OCt + ocT) * ktiles + kT) * 64 + l];
      short8 A3 = wb8[((((kyb * 2 + ty) * 4 + 3) * OCt + ocT) * ktiles + kT) * 64 + l];
      // B-frags: rows xi0 + n, xi0 in {0,1,2}
      short8 b0 = *reinterpret_cast<const short8*>(&lds[(ty * 18 + 0 + n) * 40 + koff]);
      short8 b1 = *reinterpret_cast<const short8*>(&lds[(ty * 18 + 1 + n) * 40 + koff]);
      short8 b2 = *reinterpret_cast<const short8*>(&lds[(ty * 18 + 2 + n) * 40 + koff]);
      // even ox: (kx1, xi0=1), (kx3, xi0=0); odd ox: (kx0, xi0=2), (kx2, xi0=1)
      accE = __builtin_amdgcn_mfma_f32_16x16x32_bf16(A1, b1, accE, 0, 0, 0);
      accE = __builtin_amdgcn_mfma_f32_16x16x32_bf16(A3, b0, accE, 0, 0, 0);
      accO = __builtin_amdgcn_mfma_f32_16x16x32_bf16(A0, b2, accO, 0, 0, 0);
      accO = __builtin_amdgcn_mfma_f32_16x16x32_bf16(A2, b1, accO, 0, 0, 0);
    }
  }
  // epilogue: D: col(n)=lane&15, row(oc off)=(lane>>4)*4+reg  [m89-verified]
  int ocr0 = oc0w + ((l >> 4) << 2);
  int oxE = ox0 + 2 * n;
  int oxO = ox0 + 1 + 2 * n;
#pragma unroll
  for (int r = 0; r < 4; ++r) {
    float bv = bias[ocr0 + r];
    size_t rowbase = ((size_t)(ocr0 + r) * OH + oy) * OW;
    out[rowbase + oxE] = fmaxf((accE[r] + bv) * kBNF, 0.f);
    out[rowbase + oxO] = fmaxf((accO[r] + bv) * kBNF, 0.f);
  }
}

// ---------------------------------------------------------------- final 3x3 conv 128->1 + sigmoid (R9)
__global__ __launch_bounds__(320) void dow_k(const float* __restrict__ in,
                                             const float* __restrict__ w,
                                             const float* __restrict__ bias,
                                             float* __restrict__ out) {
  const int H = 320, W = 320, IC = 128;
  int oy = blockIdx.x;
  int tx = threadIdx.x;
  __shared__ float in_s[4][3][W + 2];
  __shared__ float w_s[IC * 9];
  for (int e = tx; e < IC * 9; e += 320) w_s[e] = w[e];
  float acc = 0.f;
  for (int ic0 = 0; ic0 < IC; ic0 += 4) {
    __syncthreads();
    for (int e = tx; e < 4 * 3 * (W + 2); e += 320) {
      int icr = e / (3 * (W + 2));
      int rem = e - icr * (3 * (W + 2));
      int r = rem / (W + 2), c = rem - r * (W + 2);
      int iy = oy + r - 1, ix = c - 1;
      float v = 0.f;
      if (iy >= 0 && iy < H && ix >= 0 && ix < W)
        v = in[((ic0 + icr) * H + iy) * W + ix];
      in_s[icr][r][c] = v;
    }
    __syncthreads();
#pragma unroll
    for (int icr = 0; icr < 4; ++icr)
#pragma unroll
      for (int r = 0; r < 3; ++r)
#pragma unroll
        for (int c = 0; c < 3; ++c)
          acc = fmaf(w_s[(ic0 + icr) * 9 + r * 3 + c], in_s[icr][r][tx + c], acc);
  }
  acc += bias[0];
  out[oy * W + tx] = 1.f / (1.f + expf(-acc));
}

// ---------------------------------------------------------------- codebook sq-norms: numpy-pairwise fp32
__global__ __launch_bounds__(256) void cbprep_np(const float* __restrict__ cb,
                                                 float* __restrict__ c2f) {
  int e = blockIdx.x, t = threadIdx.x;
  __shared__ float a[256];
  a[t] = cb[e * 256 + t];
  __syncthreads();
  if (t == 0) {
    float tot = 0.f;
    for (int h = 0; h < 2; ++h) {
      const float* p = a + h * 128;
      float r[8];
#pragma unroll
      for (int j = 0; j < 8; ++j) r[j] = __fmul_rn(p[j], p[j]);
      for (int i = 8; i < 128; i += 8)
#pragma unroll
        for (int j = 0; j < 8; ++j) r[j] = __fadd_rn(r[j], __fmul_rn(p[i + j], p[i + j]));
      float s = __fadd_rn(__fadd_rn(__fadd_rn(r[0], r[1]), __fadd_rn(r[2], r[3])),
                          __fadd_rn(__fadd_rn(r[4], r[5]), __fadd_rn(r[6], r[7])));
      tot = (h == 0) ? s : __fadd_rn(tot, s);
    }
    c2f[e] = tot;
  }
}

// ---------------------------------------------------------------- VQ: parallel f2 / float4 dot / tree argmin (R13)
__global__ __launch_bounds__(256) void vq_ref_k(const float* __restrict__ z,
                                                const float* __restrict__ cb,
                                                const float* __restrict__ c2f,
                                                float* __restrict__ zq_out,
                                                float* __restrict__ idx_out) {
  int row = blockIdx.x;
  int t = threadIdx.x;
  __shared__ float f[256];
  __shared__ float dist[1024];
  __shared__ float rr[2][8];
  __shared__ float f2s;
  __shared__ float rv_s[256];
  __shared__ int ri_s[256];
  __shared__ int bestIdx;
  f[t] = z[(size_t)row * 256 + t];
  __syncthreads();
  if (t < 16) {
    int hh = t >> 3, j = t & 7;
    const float* p = f + hh * 128;
    float r = __fmul_rn(p[j], p[j]);
    for (int i = 8; i < 128; i += 8) r = __fadd_rn(r, __fmul_rn(p[i + j], p[i + j]));
    rr[hh][j] = r;
  }
  __syncthreads();
  if (t == 0) {
    float s0 = __fadd_rn(__fadd_rn(__fadd_rn(rr[0][0], rr[0][1]), __fadd_rn(rr[0][2], rr[0][3])),
                         __fadd_rn(__fadd_rn(rr[0][4], rr[0][5]), __fadd_rn(rr[0][6], rr[0][7])));
    float s1 = __fadd_rn(__fadd_rn(__fadd_rn(rr[1][0], rr[1][1]), __fadd_rn(rr[1][2], rr[1][3])),
                         __fadd_rn(__fadd_rn(rr[1][4], rr[1][5]), __fadd_rn(rr[1][6], rr[1][7])));
    f2s = __fadd_rn(s0, s1);
  }
  __syncthreads();
  float f2 = f2s;
  for (int e = t; e < 1024; e += 256) {
    const float4* cbe = reinterpret_cast<const float4*>(cb + (size_t)e * 256);
    double dot = 0.0;
    for (int d = 0; d < 64; ++d) {
      float4 c4 = cbe[d];
      float4 f4 = *reinterpret_cast<const float4*>(&f[d * 4]);
      dot = fma((double)f4.x, (double)c4.x, dot);
      dot = fma((double)f4.y, (double)c4.y, dot);
      dot = fma((double)f4.z, (double)c4.z, dot);
      dot = fma((double)f4.w, (double)c4.w, dot);
    }
    float C = __fmul_rn(2.f, (float)dot);
    dist[e] = __fsub_rn(__fadd_rn(f2, c2f[e]), C);
  }
  __syncthreads();
  float bv = dist[t];
  int bi = t;
  for (int e = t + 256; e < 1024; e += 256) {
    float v = dist[e];
    if (v < bv) { bv = v; bi = e; }
  }
  rv_s[t] = bv;
  ri_s[t] = bi;
  __syncthreads();
  for (int s = 128; s > 0; s >>= 1) {
    if (t < s) {
      float v2 = rv_s[t + s];
      int i2 = ri_s[t + s];
      if (v2 < rv_s[t] || (v2 == rv_s[t] && i2 < ri_s[t])) { rv_s[t] = v2; ri_s[t] = i2; }
    }
    __syncthreads();
  }
  if (t == 0) {
    bestIdx = ri_s[0];
    idx_out[row] = (float)ri_s[0];
  }
  __syncthreads();
  zq_out[(size_t)row * 256 + t] = cb[(size_t)bestIdx * 256 + t];
}

// ================================================================ host
extern "C" void kernel_launch(void* const* d_in, const int* in_sizes, int n_in,
                              void* d_out, int out_size, void* d_ws, size_t ws_size,
                              hipStream_t stream) {
  const float* x = (const float*)d_in[0];
  const float* w0 = (const float*)d_in[1];
  const float* b0 = (const float*)d_in[2];
  const float* a_c1w = (const float*)d_in[3];
  const float* a_c1b = (const float*)d_in[4];
  const float* a_c2w = (const float*)d_in[5];
  const float* a_c2b = (const float*)d_in[6];
  const float* a_scw = (const float*)d_in[7];
  const float* a_scb = (const float*)d_in[8];
  const float* b_c1w = (const float*)d_in[9];
  const float* b_c1b = (const float*)d_in[10];
  const float* b_c2w = (const float*)d_in[11];
  const float* b_c2b = (const float*)d_in[12];
  const float* b_scw = (const float*)d_in[13];
  const float* b_scb = (const float*)d_in[14];
  const float* ew = (const float*)d_in[15];
  const float* eb = (const float*)d_in[16];
  const float* cb = (const float*)d_in[17];
  const float* d0w = (const float*)d_in[18];
  const float* d0b = (const float*)d_in[19];
  const float* dt1w = (const float*)d_in[20];
  const float* dt1b = (const float*)d_in[21];
  const float* dt2w = (const float*)d_in[22];
  const float* dt2b = (const float*)d_in[23];
  const float* doww = (const float*)d_in[24];
  const float* dob = (const float*)d_in[25];

  // ws (floats): A 13.1M | B 6.55M | C 6.55M | c2f 1024  ~= 105 MB (unchanged)
  float* ws = (float*)d_ws;
  float* A = ws;
  float* Bf = ws + 13107200;
  float* Cf = ws + 19660800;
  float* c2f = ws + 26214400;
  // conv3x3 transposed weights (dead-region placements, audited R12)
  float* w3_ac1 = Cf;            // 294,912 f
  float* w3_ac2 = A + 6600000;   // 589,824 f
  float* w3_bc1 = Bf + 3300000;  // 1,179,648 f
  float* w3_bc2 = A + 3300000;   // 2,359,296 f
  // ConvT bf16 fragment weights (dead regions during decoder)
  __hip_bfloat16* wb_dt1 = (__hip_bfloat16*)(void*)A;              // 2,097,152 bf16 = 1.05M f
  __hip_bfloat16* wb_dt2 = (__hip_bfloat16*)(void*)(Bf + 3400000); //   524,288 bf16 = 262K f

  float* outf = (float*)d_out;
  float* recon = outf;
  float* zq = outf + 409600;
  float* idxo = zq + 6553600;

  cbprep_np<<<1024, 256, 0, stream>>>(cb, c2f);

  for (int b = 0; b < 4; ++b) {
    const float* xb = x + (size_t)b * 102400;
    float* zqb = zq + (size_t)b * 1638400;
    float* idxb = idxo + (size_t)b * 6400;
    float* reconb = recon + (size_t)b * 102400;

    // encoder (fp32; z bit-identical to passing rounds)
    conv0_k<<<320, 320, 0, stream>>>(xb, w0, b0, A);
    prep_w3_k<<<1152, 256, 0, stream>>>(a_c1w, w3_ac1, 128, 256);
    conv3x3_k<2, true, false><<<dim3(3, 160, 4), 256, 0, stream>>>(
        A, w3_ac1, a_c1b, nullptr, Bf, 128, 320, 320, 256, 160, 160);
    conv1x1_k<2, false><<<dim3(400, 4), 256, 0, stream>>>(
        A, a_scw, a_scb, Cf, 128, 320, 320, 256, 160, 160);
    prep_w3_k<<<2304, 256, 0, stream>>>(a_c2w, w3_ac2, 256, 256);
    conv3x3_k<1, true, true><<<dim3(3, 160, 4), 256, 0, stream>>>(
        Bf, w3_ac2, a_c2b, Cf, A, 256, 160, 160, 256, 160, 160);
    prep_w3_k<<<4608, 256, 0, stream>>>(b_c1w, w3_bc1, 256, 512);
    conv3x3_k<2, true, false><<<dim3(2, 80, 8), 256, 0, stream>>>(
        A, w3_bc1, b_c1b, nullptr, Bf, 256, 160, 160, 512, 80, 80);
    conv1x1_k<2, false><<<dim3(100, 8), 256, 0, stream>>>(
        A, b_scw, b_scb, Cf, 256, 160, 160, 512, 80, 80);
    prep_w3_k<<<9216, 256, 0, stream>>>(b_c2w, w3_bc2, 512, 512);
    conv3x3_k<1, true, true><<<dim3(2, 80, 8), 256, 0, stream>>>(
        Bf, w3_bc2, b_c2b, Cf, A, 512, 80, 80, 512, 80, 80);
    conv1x1_k<1, false><<<dim3(100, 4), 256, 0, stream>>>(
        A, ew, eb, Cf, 512, 80, 80, 256, 80, 80);
    // VQ (unchanged emulation)
    vq_ref_k<<<6400, 256, 0, stream>>>(Cf, cb, c2f, zqb, idxb);
    // decoder: bf16 MFMA ConvT
    prep_wb_k<<<8192, 256, 0, stream>>>(dt1w, wb_dt1, 512, 256);   // 2,097,152 el
    prep_wb_k<<<2048, 256, 0, stream>>>(dt2w, wb_dt2, 256, 128);   //   524,288 el
    conv1x1_k<1, true><<<dim3(100, 8), 256, 0, stream>>>(
        zqb, d0w, d0b, Bf, 256, 80, 80, 512, 80, 80);              // g0 = Bf
    convt_mfma_k<<<dim3(5, 160, 4), 256, 0, stream>>>(
        Bf, wb_dt1, dt1b, Cf, 512, 80, 80, 256, 160, 160);         // g1 = Cf
    convt_mfma_k<<<dim3(10, 320, 2), 256, 0, stream>>>(
        Cf, wb_dt2, dt2b, A, 256, 160, 160, 128, 320, 320);        // g2 = A
    dow_k<<<320, 320, 0, stream>>>(A, doww, dob, reconb);
  }
}

// Round 15
// 14879.039 us; speedup vs baseline: 1.3946x; 1.0753x over previous
//
#include <hip/hip_runtime.h>
#include <hip/hip_bf16.h>
#include <math.h>

// Round 15 (on R14, 16.0 ms): remove dead work, bit-exact z.
//  1. conv3x3 -> 80-px tiles / 320 threads: OW=80 grid.x=1, OW=160 grid.x=2
//     -> zero wasted FMAs (was 37.5% on b-layers, 17% on a-layers).
//     Per-output FMA chain unchanged (ic0 asc, icr asc, ky, kx) -> z bit-exact.
//  2. VQ 4 rows/block: cb float4 loads shared across rows (per-row fp64 dot
//     order unchanged); first-index argmin via wave butterfly (equivalent).
// Anchors: fp32 encoder + fp32 op-order epilogue; VQ numpy-fp32-grid emulation;
// decoder = R14 bf16 MFMA (validated); ws layout ~105 MB.

static constexpr float kBNF = 0.9999950000374997f;

typedef short short8 __attribute__((ext_vector_type(8)));
typedef float f32x4 __attribute__((ext_vector_type(4)));

// ---------------------------------------------------------------- conv0: 1->128, 3x3, s1, relu (B=1), fp32
__global__ __launch_bounds__(320) void conv0_k(const float* __restrict__ x,
                                               const float* __restrict__ w,
                                               const float* __restrict__ b,
                                               float* __restrict__ out) {
  const int H = 320, W = 320, OC = 128;
  int oy = blockIdx.x;
  int tx = threadIdx.x;
  __shared__ float in_s[3][W + 2];
  __shared__ float w_s[128 * 9];
  __shared__ float b_s[128];
  for (int e = tx; e < 3 * (W + 2); e += 320) {
    int r = e / (W + 2), c = e % (W + 2);
    int iy = oy + r - 1, ix = c - 1;
    float v = 0.f;
    if (iy >= 0 && iy < H && ix >= 0 && ix < W) v = x[iy * W + ix];
    in_s[r][c] = v;
  }
  for (int e = tx; e < 128 * 9; e += 320) w_s[e] = w[e];
  for (int e = tx; e < 128; e += 320) b_s[e] = b[e];
  __syncthreads();
  float iv[9];
#pragma unroll
  for (int r = 0; r < 3; ++r)
#pragma unroll
    for (int c = 0; c < 3; ++c) iv[r * 3 + c] = in_s[r][tx + c];
  for (int oc = 0; oc < OC; ++oc) {
    float acc = 0.f;
#pragma unroll
    for (int t = 0; t < 9; ++t) acc = fmaf(w_s[oc * 9 + t], iv[t], acc);
    float v32 = __fadd_rn(acc, b_s[oc]);
    v32 = __fmul_rn(v32, kBNF);
    out[(oc * H + oy) * W + tx] = fmaxf(v32, 0.f);
  }
}

// ---------------------------------------------------------------- conv3x3 weight transpose: w2[(ic*9+tap)*OC+oc]
__global__ __launch_bounds__(256) void prep_w3_k(const float* __restrict__ w,
                                                 float* __restrict__ w2,
                                                 int IC, int OC) {
  int i = blockIdx.x * 256 + threadIdx.x;
  int total = IC * OC * 9;
  if (i >= total) return;
  int oc = i % OC;
  int rest = i / OC;
  int tap = rest % 9;
  int ic = rest / 9;
  w2[i] = w[((size_t)oc * IC + ic) * 9 + tap];
}

// ---------------------------------------------------------------- 3x3 conv: 80-px tile, 320 threads, ICS=8
// threads: 20 px-groups x 16 oc-groups; thread = 4px x 4oc. FMA order per
// output identical to R9/R13 -> z bit-exact.
template <int S, bool RELU, bool HAS_SKIP>
__global__ __launch_bounds__(320) void conv3x3_k(
    const float* __restrict__ in, const float* __restrict__ w2,
    const float* __restrict__ bias, const float* __restrict__ skip,
    float* __restrict__ out, int IC, int IH, int IW, int OC, int OH, int OW) {
  // S=1: in_f[icr][ky][84] plain cols (82 used)
  // S=2: in_f[icr][ky][168]: [0..83]=even cols, [84..167]=odd cols (81/81 used)
  __shared__ float in_f[8][3][(S == 1) ? 84 : 168];
  __shared__ float w_f[8][9][64];
  int t = threadIdx.x;
  int ox0 = blockIdx.x * 80;
  int oy = blockIdx.y;
  int oc0 = blockIdx.z * 64;
  int oc4 = (t / 20) * 4, px4 = (t % 20) * 4;
  float acc[4][4] = {};
  const int NCOL = 80 * S + 2;  // 82 or 162
  const int NIN = 8 * 3 * NCOL;
  for (int ic0 = 0; ic0 < IC; ic0 += 8) {
    __syncthreads();
    for (int e = t; e < NIN; e += 320) {
      int icr = e / (3 * NCOL);
      int rem = e - icr * (3 * NCOL);
      int r = rem / NCOL, c = rem - r * NCOL;
      int iy = oy * S - 1 + r;
      int ix = ox0 * S - 1 + c;
      float v = 0.f;
      if (iy >= 0 && iy < IH && ix >= 0 && ix < IW)
        v = in[((ic0 + icr) * IH + iy) * IW + ix];
      if (S == 1)
        in_f[icr][r][c] = v;
      else
        in_f[icr][r][(c & 1) * 84 + (c >> 1)] = v;
    }
    for (int e = t; e < 8 * 9 * 64; e += 320) {
      int ocr = e & 63;
      int rem = e >> 6;
      int tap = rem % 9, icr = rem / 9;
      w_f[icr][tap][ocr] = w2[((size_t)(ic0 + icr) * 9 + tap) * OC + oc0 + ocr];
    }
    __syncthreads();
#pragma unroll
    for (int icr = 0; icr < 8; ++icr) {
#pragma unroll
      for (int ky = 0; ky < 3; ++ky) {
        float iv[9];
        if (S == 1) {
          float4 va = *reinterpret_cast<const float4*>(&in_f[icr][ky][px4]);
          float2 vb = *reinterpret_cast<const float2*>(&in_f[icr][ky][px4 + 4]);
          iv[0] = va.x; iv[1] = va.y; iv[2] = va.z;
          iv[3] = va.w; iv[4] = vb.x; iv[5] = vb.y;
        } else {
          float4 ve = *reinterpret_cast<const float4*>(&in_f[icr][ky][px4]);
          float se = in_f[icr][ky][px4 + 4];
          float4 vo = *reinterpret_cast<const float4*>(&in_f[icr][ky][84 + px4]);
          iv[0] = ve.x; iv[1] = ve.y; iv[2] = ve.z;
          iv[3] = ve.w; iv[4] = se;
          iv[5] = vo.x; iv[6] = vo.y; iv[7] = vo.z; iv[8] = vo.w;
        }
#pragma unroll
        for (int kx = 0; kx < 3; ++kx) {
          float4 wv = *reinterpret_cast<const float4*>(&w_f[icr][ky * 3 + kx][oc4]);
          const float* wp = (const float*)&wv;
#pragma unroll
          for (int p = 0; p < 4; ++p) {
            float ivv;
            if (S == 1) {
              ivv = iv[p + kx];
            } else {
              ivv = (kx == 0) ? iv[p] : (kx == 1) ? iv[5 + p] : iv[p + 1];
            }
#pragma unroll
            for (int o = 0; o < 4; ++o)
              acc[o][p] = fmaf(wp[o], ivv, acc[o][p]);
          }
        }
      }
    }
  }
  int opx = ox0 + px4;
  if (opx < OW) {
#pragma unroll
    for (int o = 0; o < 4; ++o) {
      int oc = oc0 + oc4 + o;
      float bv = bias[oc];
      size_t base = ((size_t)oc * OH + oy) * OW + opx;
      float4 rv;
      float* rp = (float*)&rv;
#pragma unroll
      for (int p = 0; p < 4; ++p) {
        float v32 = __fadd_rn(acc[o][p], bv);
        v32 = __fmul_rn(v32, kBNF);
        if (HAS_SKIP) v32 = __fadd_rn(v32, skip[base + p]);
        if (RELU) v32 = fmaxf(v32, 0.f);
        rp[p] = v32;
      }
      *reinterpret_cast<float4*>(&out[base]) = rv;
    }
  }
}

// ---------------------------------------------------------------- 1x1 conv, fp32 acc
template <int S, bool RELU>
__global__ __launch_bounds__(256) void conv1x1_k(
    const float* __restrict__ in, const float* __restrict__ w,
    const float* __restrict__ bias, float* __restrict__ out,
    int IC, int IH, int IW, int OC, int OH, int OW) {
  __shared__ float in_s[16][64];
  __shared__ float w_s[16][64];
  const int P = OH * OW;
  int t = threadIdx.x;
  int p0 = blockIdx.x * 64;
  int oc0 = blockIdx.y * 64;
  int oc4 = (t >> 4) * 4, px4 = (t & 15) * 4;
  float acc[4][4] = {};
  for (int ic0 = 0; ic0 < IC; ic0 += 16) {
    __syncthreads();
    {
      int e = t;
#pragma unroll
      for (int k = 0; k < 4; ++k, e += 256) {
        int icr = e >> 6, pxr = e & 63;
        int p = p0 + pxr;
        float v = 0.f;
        if (p < P) {
          int oy = p / OW, ox = p % OW;
          v = in[((ic0 + icr) * IH + oy * S) * IW + ox * S];
        }
        in_s[icr][pxr] = v;
      }
      e = t;
#pragma unroll
      for (int k = 0; k < 4; ++k, e += 256) {
        int icr = e >> 6, ocr = e & 63;
        w_s[icr][ocr] = w[(oc0 + ocr) * IC + ic0 + icr];
      }
    }
    __syncthreads();
#pragma unroll
    for (int icr = 0; icr < 16; ++icr) {
      float4 iv = *reinterpret_cast<const float4*>(&in_s[icr][px4]);
      float4 wv = *reinterpret_cast<const float4*>(&w_s[icr][oc4]);
      const float* ip = (const float*)&iv;
      const float* wp = (const float*)&wv;
#pragma unroll
      for (int o = 0; o < 4; ++o)
#pragma unroll
        for (int p = 0; p < 4; ++p)
          acc[o][p] = fmaf(wp[o], ip[p], acc[o][p]);
    }
  }
  int p = p0 + px4;
  if (p < P) {
    int oy = p / OW, ox = p % OW;
#pragma unroll
    for (int o = 0; o < 4; ++o) {
      int oc = oc0 + oc4 + o;
      float bv = bias[oc];
      float4 rv;
      float* rp = (float*)&rv;
#pragma unroll
      for (int pp = 0; pp < 4; ++pp) {
        float v32 = __fadd_rn(acc[o][pp], bv);
        v32 = __fmul_rn(v32, kBNF);
        if (RELU) v32 = fmaxf(v32, 0.f);
        rp[pp] = v32;
      }
      *reinterpret_cast<float4*>(&out[((size_t)oc * OH + oy) * OW + ox]) = rv;
    }
  }
}

// ---------------------------------------------------------------- ConvT weight prep -> bf16 A-fragments (R14)
__global__ __launch_bounds__(256) void prep_wb_k(const float* __restrict__ w,
                                                 __hip_bfloat16* __restrict__ wb,
                                                 int IC, int OC) {
  int i = blockIdx.x * 256 + threadIdx.x;
  int total = 16 * IC * OC;
  if (i >= total) return;
  int per_cfg = IC * OC;
  int cfg = i / per_cfg;
  int r = i - cfg * per_cfg;
  int ktiles = IC >> 5;
  int ocT = r / (ktiles * 512);
  int r2 = r - ocT * (ktiles * 512);
  int kT = r2 >> 9;
  int f = r2 & 511;
  int lane = f >> 3, e = f & 7;
  int m = lane & 15, kk = ((lane >> 4) << 3) + e;
  int oc = ocT * 16 + m, ic = kT * 32 + kk;
  int kyb = cfg >> 3, ty = (cfg >> 2) & 1, kx = cfg & 3;
  int ky = kyb + 2 * ty;
  wb[i] = __float2bfloat16(w[((size_t)ic * OC + oc) * 16 + ky * 4 + kx]);
}

// ---------------------------------------------------------------- ConvT k4 s2 p1 via MFMA bf16 (R14, validated)
__global__ __launch_bounds__(256) void convt_mfma_k(
    const float* __restrict__ in, const __hip_bfloat16* __restrict__ wb,
    const float* __restrict__ bias, float* __restrict__ out,
    int IC, int IH, int IW, int OC, int OH, int OW) {
  __shared__ __align__(16) __hip_bfloat16 lds[2 * 18 * 40];
  int t = threadIdx.x;
  int wv = t >> 6, l = t & 63;
  int ox0 = blockIdx.x * 32;
  int oy = blockIdx.y;
  int oc0w = blockIdx.z * 64 + wv * 16;
  int kyb = (oy & 1) ? 0 : 1;
  int hb = ox0 >> 1;
  int iy0n = oy + 1 - kyb;
  int iy0 = iy0n >> 1;
  bool ok0 = (iy0 < IH);
  int iy1n = oy + 1 - kyb - 2;
  int iy1 = iy1n >> 1;
  bool ok1 = (iy1n >= 0) && (iy1 < IH);
  f32x4 accE = {0.f, 0.f, 0.f, 0.f};
  f32x4 accO = {0.f, 0.f, 0.f, 0.f};
  const int ktiles = IC >> 5;
  int n = l & 15, koff = (l >> 4) * 8;
  const short8* wb8 = reinterpret_cast<const short8*>(wb);
  int ocT = oc0w >> 4;
  const int OCt = OC >> 4;
  for (int kT = 0; kT < ktiles; ++kT) {
    __syncthreads();
    for (int e = t; e < 1152; e += 256) {
      int ic = e / 36;
      int r = e - ic * 36;
      int ty = r / 18, xi = r - ty * 18;
      int ix = hb - 1 + xi;
      int iy = ty ? iy1 : iy0;
      bool ok = ty ? ok1 : ok0;
      float v = 0.f;
      if (ok && ix >= 0 && ix < IW)
        v = in[((size_t)(kT * 32 + ic) * IH + iy) * IW + ix];
      lds[(ty * 18 + xi) * 40 + ic] = __float2bfloat16(v);
    }
    __syncthreads();
#pragma unroll
    for (int ty = 0; ty < 2; ++ty) {
      short8 A0 = wb8[((((kyb * 2 + ty) * 4 + 0) * OCt + ocT) * ktiles + kT) * 64 + l];
      short8 A1 = wb8[((((kyb * 2 + ty) * 4 + 1) * OCt + ocT) * ktiles + kT) * 64 + l];
      short8 A2 = wb8[((((kyb * 2 + ty) * 4 + 2) * OCt + ocT) * ktiles + kT) * 64 + l];
      short8 A3 = wb8[((((kyb * 2 + ty) * 4 + 3) * OCt + ocT) * ktiles + kT) * 64 + l];
      short8 b0 = *reinterpret_cast<const short8*>(&lds[(ty * 18 + 0 + n) * 40 + koff]);
      short8 b1 = *reinterpret_cast<const short8*>(&lds[(ty * 18 + 1 + n) * 40 + koff]);
      short8 b2 = *reinterpret_cast<const short8*>(&lds[(ty * 18 + 2 + n) * 40 + koff]);
      accE = __builtin_amdgcn_mfma_f32_16x16x32_bf16(A1, b1, accE, 0, 0, 0);
      accE = __builtin_amdgcn_mfma_f32_16x16x32_bf16(A3, b0, accE, 0, 0, 0);
      accO = __builtin_amdgcn_mfma_f32_16x16x32_bf16(A0, b2, accO, 0, 0, 0);
      accO = __builtin_amdgcn_mfma_f32_16x16x32_bf16(A2, b1, accO, 0, 0, 0);
    }
  }
  int ocr0 = oc0w + ((l >> 4) << 2);
  int oxE = ox0 + 2 * n;
  int oxO = ox0 + 1 + 2 * n;
#pragma unroll
  for (int r = 0; r < 4; ++r) {
    float bv = bias[ocr0 + r];
    size_t rowbase = ((size_t)(ocr0 + r) * OH + oy) * OW;
    out[rowbase + oxE] = fmaxf((accE[r] + bv) * kBNF, 0.f);
    out[rowbase + oxO] = fmaxf((accO[r] + bv) * kBNF, 0.f);
  }
}

// ---------------------------------------------------------------- final 3x3 conv 128->1 + sigmoid (R9)
__global__ __launch_bounds__(320) void dow_k(const float* __restrict__ in,
                                             const float* __restrict__ w,
                                             const float* __restrict__ bias,
                                             float* __restrict__ out) {
  const int H = 320, W = 320, IC = 128;
  int oy = blockIdx.x;
  int tx = threadIdx.x;
  __shared__ float in_s[4][3][W + 2];
  __shared__ float w_s[IC * 9];
  for (int e = tx; e < IC * 9; e += 320) w_s[e] = w[e];
  float acc = 0.f;
  for (int ic0 = 0; ic0 < IC; ic0 += 4) {
    __syncthreads();
    for (int e = tx; e < 4 * 3 * (W + 2); e += 320) {
      int icr = e / (3 * (W + 2));
      int rem = e - icr * (3 * (W + 2));
      int r = rem / (W + 2), c = rem - r * (W + 2);
      int iy = oy + r - 1, ix = c - 1;
      float v = 0.f;
      if (iy >= 0 && iy < H && ix >= 0 && ix < W)
        v = in[((ic0 + icr) * H + iy) * W + ix];
      in_s[icr][r][c] = v;
    }
    __syncthreads();
#pragma unroll
    for (int icr = 0; icr < 4; ++icr)
#pragma unroll
      for (int r = 0; r < 3; ++r)
#pragma unroll
        for (int c = 0; c < 3; ++c)
          acc = fmaf(w_s[(ic0 + icr) * 9 + r * 3 + c], in_s[icr][r][tx + c], acc);
  }
  acc += bias[0];
  out[oy * W + tx] = 1.f / (1.f + expf(-acc));
}

// ---------------------------------------------------------------- codebook sq-norms: numpy-pairwise fp32
__global__ __launch_bounds__(256) void cbprep_np(const float* __restrict__ cb,
                                                 float* __restrict__ c2f) {
  int e = blockIdx.x, t = threadIdx.x;
  __shared__ float a[256];
  a[t] = cb[e * 256 + t];
  __syncthreads();
  if (t == 0) {
    float tot = 0.f;
    for (int h = 0; h < 2; ++h) {
      const float* p = a + h * 128;
      float r[8];
#pragma unroll
      for (int j = 0; j < 8; ++j) r[j] = __fmul_rn(p[j], p[j]);
      for (int i = 8; i < 128; i += 8)
#pragma unroll
        for (int j = 0; j < 8; ++j) r[j] = __fadd_rn(r[j], __fmul_rn(p[i + j], p[i + j]));
      float s = __fadd_rn(__fadd_rn(__fadd_rn(r[0], r[1]), __fadd_rn(r[2], r[3])),
                          __fadd_rn(__fadd_rn(r[4], r[5]), __fadd_rn(r[6], r[7])));
      tot = (h == 0) ? s : __fadd_rn(tot, s);
    }
    c2f[e] = tot;
  }
}

// ---------------------------------------------------------------- VQ: 4 rows/block; per-row arithmetic identical
__global__ __launch_bounds__(256) void vq_ref_k(const float* __restrict__ z,
                                                const float* __restrict__ cb,
                                                const float* __restrict__ c2f,
                                                float* __restrict__ zq_out,
                                                float* __restrict__ idx_out) {
  int n0 = blockIdx.x * 4;
  int t = threadIdx.x;
  __shared__ float f[4][256];
  __shared__ float dist[4][1024];
  __shared__ float rr[4][2][8];
  __shared__ float f2s[4];
  __shared__ int bestIdx[4];
  for (int e = t; e < 1024; e += 256) {
    int r = e >> 8, c = e & 255;
    f[r][c] = z[(size_t)(n0 + r) * 256 + c];
  }
  __syncthreads();
  // numpy-pairwise f2 partials: 4 rows x 16 partial-threads
  if (t < 64) {
    int row = t >> 4, hh = (t >> 3) & 1, j = t & 7;
    const float* p = f[row] + hh * 128;
    float r = __fmul_rn(p[j], p[j]);
    for (int i = 8; i < 128; i += 8) r = __fadd_rn(r, __fmul_rn(p[i + j], p[i + j]));
    rr[row][hh][j] = r;
  }
  __syncthreads();
  if (t < 4) {
    float s0 = __fadd_rn(__fadd_rn(__fadd_rn(rr[t][0][0], rr[t][0][1]), __fadd_rn(rr[t][0][2], rr[t][0][3])),
                         __fadd_rn(__fadd_rn(rr[t][0][4], rr[t][0][5]), __fadd_rn(rr[t][0][6], rr[t][0][7])));
    float s1 = __fadd_rn(__fadd_rn(__fadd_rn(rr[t][1][0], rr[t][1][1]), __fadd_rn(rr[t][1][2], rr[t][1][3])),
                         __fadd_rn(__fadd_rn(rr[t][1][4], rr[t][1][5]), __fadd_rn(rr[t][1][6], rr[t][1][7])));
    f2s[t] = __fadd_rn(s0, s1);
  }
  __syncthreads();
  // 4 entries per thread, cb loaded once per entry, 4 row-accumulators
  for (int e = t; e < 1024; e += 256) {
    const float4* cbe = reinterpret_cast<const float4*>(cb + (size_t)e * 256);
    double d0 = 0.0, d1 = 0.0, d2 = 0.0, d3 = 0.0;
    for (int d = 0; d < 64; ++d) {
      float4 c4 = cbe[d];
      float4 f0 = *reinterpret_cast<const float4*>(&f[0][d * 4]);
      float4 f1 = *reinterpret_cast<const float4*>(&f[1][d * 4]);
      float4 f2v = *reinterpret_cast<const float4*>(&f[2][d * 4]);
      float4 f3 = *reinterpret_cast<const float4*>(&f[3][d * 4]);
      d0 = fma((double)f0.x, (double)c4.x, d0); d0 = fma((double)f0.y, (double)c4.y, d0);
      d0 = fma((double)f0.z, (double)c4.z, d0); d0 = fma((double)f0.w, (double)c4.w, d0);
      d1 = fma((double)f1.x, (double)c4.x, d1); d1 = fma((double)f1.y, (double)c4.y, d1);
      d1 = fma((double)f1.z, (double)c4.z, d1); d1 = fma((double)f1.w, (double)c4.w, d1);
      d2 = fma((double)f2v.x, (double)c4.x, d2); d2 = fma((double)f2v.y, (double)c4.y, d2);
      d2 = fma((double)f2v.z, (double)c4.z, d2); d2 = fma((double)f2v.w, (double)c4.w, d2);
      d3 = fma((double)f3.x, (double)c4.x, d3); d3 = fma((double)f3.y, (double)c4.y, d3);
      d3 = fma((double)f3.z, (double)c4.z, d3); d3 = fma((double)f3.w, (double)c4.w, d3);
    }
    float c2e = c2f[e];
    dist[0][e] = __fsub_rn(__fadd_rn(f2s[0], c2e), __fmul_rn(2.f, (float)d0));
    dist[1][e] = __fsub_rn(__fadd_rn(f2s[1], c2e), __fmul_rn(2.f, (float)d1));
    dist[2][e] = __fsub_rn(__fadd_rn(f2s[2], c2e), __fmul_rn(2.f, (float)d2));
    dist[3][e] = __fsub_rn(__fadd_rn(f2s[3], c2e), __fmul_rn(2.f, (float)d3));
  }
  __syncthreads();
  // wave w handles row w: lane scans ascending indices, butterfly keeps lowest index on ties
  {
    int row = t >> 6, l = t & 63;
    float bv = dist[row][l];
    int bi = l;
    for (int e = l + 64; e < 1024; e += 64) {
      float v = dist[row][e];
      if (v < bv) { bv = v; bi = e; }
    }
#pragma unroll
    for (int m = 1; m < 64; m <<= 1) {
      float ov = __shfl_xor(bv, m, 64);
      int oi = __shfl_xor(bi, m, 64);
      if (ov < bv || (ov == bv && oi < bi)) { bv = ov; bi = oi; }
    }
    if (l == 0) {
      bestIdx[row] = bi;
      idx_out[n0 + row] = (float)bi;
    }
  }
  __syncthreads();
#pragma unroll
  for (int r = 0; r < 4; ++r)
    zq_out[(size_t)(n0 + r) * 256 + t] = cb[(size_t)bestIdx[r] * 256 + t];
}

// ================================================================ host
extern "C" void kernel_launch(void* const* d_in, const int* in_sizes, int n_in,
                              void* d_out, int out_size, void* d_ws, size_t ws_size,
                              hipStream_t stream) {
  const float* x = (const float*)d_in[0];
  const float* w0 = (const float*)d_in[1];
  const float* b0 = (const float*)d_in[2];
  const float* a_c1w = (const float*)d_in[3];
  const float* a_c1b = (const float*)d_in[4];
  const float* a_c2w = (const float*)d_in[5];
  const float* a_c2b = (const float*)d_in[6];
  const float* a_scw = (const float*)d_in[7];
  const float* a_scb = (const float*)d_in[8];
  const float* b_c1w = (const float*)d_in[9];
  const float* b_c1b = (const float*)d_in[10];
  const float* b_c2w = (const float*)d_in[11];
  const float* b_c2b = (const float*)d_in[12];
  const float* b_scw = (const float*)d_in[13];
  const float* b_scb = (const float*)d_in[14];
  const float* ew = (const float*)d_in[15];
  const float* eb = (const float*)d_in[16];
  const float* cb = (const float*)d_in[17];
  const float* d0w = (const float*)d_in[18];
  const float* d0b = (const float*)d_in[19];
  const float* dt1w = (const float*)d_in[20];
  const float* dt1b = (const float*)d_in[21];
  const float* dt2w = (const float*)d_in[22];
  const float* dt2b = (const float*)d_in[23];
  const float* doww = (const float*)d_in[24];
  const float* dob = (const float*)d_in[25];

  // ws (floats): A 13.1M | B 6.55M | C 6.55M | c2f 1024  ~= 105 MB (unchanged)
  float* ws = (float*)d_ws;
  float* A = ws;
  float* Bf = ws + 13107200;
  float* Cf = ws + 19660800;
  float* c2f = ws + 26214400;
  float* w3_ac1 = Cf;
  float* w3_ac2 = A + 6600000;
  float* w3_bc1 = Bf + 3300000;
  float* w3_bc2 = A + 3300000;
  __hip_bfloat16* wb_dt1 = (__hip_bfloat16*)(void*)A;
  __hip_bfloat16* wb_dt2 = (__hip_bfloat16*)(void*)(Bf + 3400000);

  float* outf = (float*)d_out;
  float* recon = outf;
  float* zq = outf + 409600;
  float* idxo = zq + 6553600;

  cbprep_np<<<1024, 256, 0, stream>>>(cb, c2f);

  for (int b = 0; b < 4; ++b) {
    const float* xb = x + (size_t)b * 102400;
    float* zqb = zq + (size_t)b * 1638400;
    float* idxb = idxo + (size_t)b * 6400;
    float* reconb = recon + (size_t)b * 102400;

    // encoder (fp32; z bit-identical)
    conv0_k<<<320, 320, 0, stream>>>(xb, w0, b0, A);
    prep_w3_k<<<1152, 256, 0, stream>>>(a_c1w, w3_ac1, 128, 256);
    conv3x3_k<2, true, false><<<dim3(2, 160, 4), 320, 0, stream>>>(
        A, w3_ac1, a_c1b, nullptr, Bf, 128, 320, 320, 256, 160, 160);
    conv1x1_k<2, false><<<dim3(400, 4), 256, 0, stream>>>(
        A, a_scw, a_scb, Cf, 128, 320, 320, 256, 160, 160);
    prep_w3_k<<<2304, 256, 0, stream>>>(a_c2w, w3_ac2, 256, 256);
    conv3x3_k<1, true, true><<<dim3(2, 160, 4), 320, 0, stream>>>(
        Bf, w3_ac2, a_c2b, Cf, A, 256, 160, 160, 256, 160, 160);
    prep_w3_k<<<4608, 256, 0, stream>>>(b_c1w, w3_bc1, 256, 512);
    conv3x3_k<2, true, false><<<dim3(1, 80, 8), 320, 0, stream>>>(
        A, w3_bc1, b_c1b, nullptr, Bf, 256, 160, 160, 512, 80, 80);
    conv1x1_k<2, false><<<dim3(100, 8), 256, 0, stream>>>(
        A, b_scw, b_scb, Cf, 256, 160, 160, 512, 80, 80);
    prep_w3_k<<<9216, 256, 0, stream>>>(b_c2w, w3_bc2, 512, 512);
    conv3x3_k<1, true, true><<<dim3(1, 80, 8), 320, 0, stream>>>(
        Bf, w3_bc2, b_c2b, Cf, A, 512, 80, 80, 512, 80, 80);
    conv1x1_k<1, false><<<dim3(100, 4), 256, 0, stream>>>(
        A, ew, eb, Cf, 512, 80, 80, 256, 80, 80);
    // VQ (4 rows/block, per-row arithmetic identical)
    vq_ref_k<<<1600, 256, 0, stream>>>(Cf, cb, c2f, zqb, idxb);
    // decoder: bf16 MFMA ConvT (R14)
    prep_wb_k<<<8192, 256, 0, stream>>>(dt1w, wb_dt1, 512, 256);
    prep_wb_k<<<2048, 256, 0, stream>>>(dt2w, wb_dt2, 256, 128);
    conv1x1_k<1, true><<<dim3(100, 8), 256, 0, stream>>>(
        zqb, d0w, d0b, Bf, 256, 80, 80, 512, 80, 80);
    convt_mfma_k<<<dim3(5, 160, 4), 256, 0, stream>>>(
        Bf, wb_dt1, dt1b, Cf, 512, 80, 80, 256, 160, 160);
    convt_mfma_k<<<dim3(10, 320, 2), 256, 0, stream>>>(
        Cf, wb_dt2, dt2b, A, 256, 160, 160, 128, 320, 320);
    dow_k<<<320, 320, 0, stream>>>(A, doww, dob, reconb);
  }
}

// Round 17
// 10365.549 us; speedup vs baseline: 2.0018x; 1.4354x over previous
//
#include <hip/hip_runtime.h>
#include <hip/hip_bf16.h>
#include <math.h>

// Round 17: R16's S=1 MFMA encoder convs switched bf16-split -> FP16-SPLIT
// (hi=fp16(v), lo=fp16(v-hi); AhiBhi+AhiBlo+AloBhi; residual ~2^-24 -> z error
// at fp32-accumulation noise level, the band proven flip-free in R9).
// Everything else identical to R16 (= R15 + MFMA encoder): S=2 fp32 convs,
// conv0, conv1x1, VQ fp32-grid emulation, bf16-MFMA decoder, ws layout.
// Diagnostic: absmax == 3.814697e-06 iff zero argmin flips.

static constexpr float kBNF = 0.9999950000374997f;

typedef short short8 __attribute__((ext_vector_type(8)));
typedef _Float16 half8 __attribute__((ext_vector_type(8)));
typedef float f32x4 __attribute__((ext_vector_type(4)));

// ---------------------------------------------------------------- conv0: 1->128, 3x3, s1, relu (B=1), fp32
__global__ __launch_bounds__(320) void conv0_k(const float* __restrict__ x,
                                               const float* __restrict__ w,
                                               const float* __restrict__ b,
                                               float* __restrict__ out) {
  const int H = 320, W = 320, OC = 128;
  int oy = blockIdx.x;
  int tx = threadIdx.x;
  __shared__ float in_s[3][W + 2];
  __shared__ float w_s[128 * 9];
  __shared__ float b_s[128];
  for (int e = tx; e < 3 * (W + 2); e += 320) {
    int r = e / (W + 2), c = e % (W + 2);
    int iy = oy + r - 1, ix = c - 1;
    float v = 0.f;
    if (iy >= 0 && iy < H && ix >= 0 && ix < W) v = x[iy * W + ix];
    in_s[r][c] = v;
  }
  for (int e = tx; e < 128 * 9; e += 320) w_s[e] = w[e];
  for (int e = tx; e < 128; e += 320) b_s[e] = b[e];
  __syncthreads();
  float iv[9];
#pragma unroll
  for (int r = 0; r < 3; ++r)
#pragma unroll
    for (int c = 0; c < 3; ++c) iv[r * 3 + c] = in_s[r][tx + c];
  for (int oc = 0; oc < OC; ++oc) {
    float acc = 0.f;
#pragma unroll
    for (int t = 0; t < 9; ++t) acc = fmaf(w_s[oc * 9 + t], iv[t], acc);
    float v32 = __fadd_rn(acc, b_s[oc]);
    v32 = __fmul_rn(v32, kBNF);
    out[(oc * H + oy) * W + tx] = fmaxf(v32, 0.f);
  }
}

// ---------------------------------------------------------------- conv3x3 weight transpose (fp32, S=2 layers)
__global__ __launch_bounds__(256) void prep_w3_k(const float* __restrict__ w,
                                                 float* __restrict__ w2,
                                                 int IC, int OC) {
  int i = blockIdx.x * 256 + threadIdx.x;
  int total = IC * OC * 9;
  if (i >= total) return;
  int oc = i % OC;
  int rest = i / OC;
  int tap = rest % 9;
  int ic = rest / 9;
  w2[i] = w[((size_t)oc * IC + ic) * 9 + tap];
}

// ---------------------------------------------------------------- 3x3 conv S=2 (R15, bit-exact order)
template <int S, bool RELU, bool HAS_SKIP>
__global__ __launch_bounds__(320) void conv3x3_k(
    const float* __restrict__ in, const float* __restrict__ w2,
    const float* __restrict__ bias, const float* __restrict__ skip,
    float* __restrict__ out, int IC, int IH, int IW, int OC, int OH, int OW) {
  __shared__ float in_f[8][3][(S == 1) ? 84 : 168];
  __shared__ float w_f[8][9][64];
  int t = threadIdx.x;
  int ox0 = blockIdx.x * 80;
  int oy = blockIdx.y;
  int oc0 = blockIdx.z * 64;
  int oc4 = (t / 20) * 4, px4 = (t % 20) * 4;
  float acc[4][4] = {};
  const int NCOL = 80 * S + 2;
  const int NIN = 8 * 3 * NCOL;
  for (int ic0 = 0; ic0 < IC; ic0 += 8) {
    __syncthreads();
    for (int e = t; e < NIN; e += 320) {
      int icr = e / (3 * NCOL);
      int rem = e - icr * (3 * NCOL);
      int r = rem / NCOL, c = rem - r * NCOL;
      int iy = oy * S - 1 + r;
      int ix = ox0 * S - 1 + c;
      float v = 0.f;
      if (iy >= 0 && iy < IH && ix >= 0 && ix < IW)
        v = in[((ic0 + icr) * IH + iy) * IW + ix];
      if (S == 1)
        in_f[icr][r][c] = v;
      else
        in_f[icr][r][(c & 1) * 84 + (c >> 1)] = v;
    }
    for (int e = t; e < 8 * 9 * 64; e += 320) {
      int ocr = e & 63;
      int rem = e >> 6;
      int tap = rem % 9, icr = rem / 9;
      w_f[icr][tap][ocr] = w2[((size_t)(ic0 + icr) * 9 + tap) * OC + oc0 + ocr];
    }
    __syncthreads();
#pragma unroll
    for (int icr = 0; icr < 8; ++icr) {
#pragma unroll
      for (int ky = 0; ky < 3; ++ky) {
        float iv[9];
        if (S == 1) {
          float4 va = *reinterpret_cast<const float4*>(&in_f[icr][ky][px4]);
          float2 vb = *reinterpret_cast<const float2*>(&in_f[icr][ky][px4 + 4]);
          iv[0] = va.x; iv[1] = va.y; iv[2] = va.z;
          iv[3] = va.w; iv[4] = vb.x; iv[5] = vb.y;
        } else {
          float4 ve = *reinterpret_cast<const float4*>(&in_f[icr][ky][px4]);
          float se = in_f[icr][ky][px4 + 4];
          float4 vo = *reinterpret_cast<const float4*>(&in_f[icr][ky][84 + px4]);
          iv[0] = ve.x; iv[1] = ve.y; iv[2] = ve.z;
          iv[3] = ve.w; iv[4] = se;
          iv[5] = vo.x; iv[6] = vo.y; iv[7] = vo.z; iv[8] = vo.w;
        }
#pragma unroll
        for (int kx = 0; kx < 3; ++kx) {
          float4 wv = *reinterpret_cast<const float4*>(&w_f[icr][ky * 3 + kx][oc4]);
          const float* wp = (const float*)&wv;
#pragma unroll
          for (int p = 0; p < 4; ++p) {
            float ivv;
            if (S == 1) {
              ivv = iv[p + kx];
            } else {
              ivv = (kx == 0) ? iv[p] : (kx == 1) ? iv[5 + p] : iv[p + 1];
            }
#pragma unroll
            for (int o = 0; o < 4; ++o)
              acc[o][p] = fmaf(wp[o], ivv, acc[o][p]);
          }
        }
      }
    }
  }
  int opx = ox0 + px4;
  if (opx < OW) {
#pragma unroll
    for (int o = 0; o < 4; ++o) {
      int oc = oc0 + oc4 + o;
      float bv = bias[oc];
      size_t base = ((size_t)oc * OH + oy) * OW + opx;
      float4 rv;
      float* rp = (float*)&rv;
#pragma unroll
      for (int p = 0; p < 4; ++p) {
        float v32 = __fadd_rn(acc[o][p], bv);
        v32 = __fmul_rn(v32, kBNF);
        if (HAS_SKIP) v32 = __fadd_rn(v32, skip[base + p]);
        if (RELU) v32 = fmaxf(v32, 0.f);
        rp[p] = v32;
      }
      *reinterpret_cast<float4*>(&out[base]) = rv;
    }
  }
}

// ---------------------------------------------------------------- S=1 conv weight prep -> fp16-split A-frags
// layout: ((((split*9+tap)*(OC/16)+ocT)*(IC/32)+kT)*64+lane)*8+e
__global__ __launch_bounds__(256) void prep_w3h_k(const float* __restrict__ w,
                                                  _Float16* __restrict__ wh,
                                                  int IC, int OC) {
  int i = blockIdx.x * 256 + threadIdx.x;
  int total = 2 * 9 * IC * OC;
  if (i >= total) return;
  int e = i & 7;
  int lane = (i >> 3) & 63;
  int rest = i >> 9;
  int ktiles = IC >> 5;
  int kT = rest % ktiles;
  int rest2 = rest / ktiles;
  int OCt = OC >> 4;
  int ocT = rest2 % OCt;
  int rest3 = rest2 / OCt;
  int tap = rest3 % 9;
  int split = rest3 / 9;
  int m = lane & 15, k = ((lane >> 4) << 3) + e;
  int oc = ocT * 16 + m, ic = kT * 32 + k;
  float v = w[((size_t)oc * IC + ic) * 9 + tap];
  _Float16 hi = (_Float16)v;
  wh[i] = (split == 0) ? hi : (_Float16)(v - (float)hi);
}

// ---------------------------------------------------------------- 3x3 conv S=1 via MFMA fp16-split
// wave = 16oc x 16px; block = 4 waves; grid (HW/16, HW, OC/64); 27 MFMA/kT.
__global__ __launch_bounds__(256) void conv3s1_mfma_k(
    const float* __restrict__ in, const _Float16* __restrict__ wh,
    const float* __restrict__ bias, const float* __restrict__ skip,
    float* __restrict__ out, int IC, int HW_, int OC) {
  __shared__ __align__(16) _Float16 ldsH[3 * 20 * 40];
  __shared__ __align__(16) _Float16 ldsL[3 * 20 * 40];
  int t = threadIdx.x;
  int wv = t >> 6, l = t & 63;
  int px0 = blockIdx.x * 16;
  int oy = blockIdx.y;
  int ocT = blockIdx.z * 4 + wv;
  const int ktiles = IC >> 5;
  const int OCt = OC >> 4;
  int n = l & 15, koff = (l >> 4) * 8;
  f32x4 acc = {0.f, 0.f, 0.f, 0.f};
  const half8* wh8 = reinterpret_cast<const half8*>(wh);
  for (int kT = 0; kT < ktiles; ++kT) {
    __syncthreads();
    for (int e = t; e < 1728; e += 256) {  // 3 rows * 18 xi * 32 ic
      int xi = e % 18;
      int rem = e / 18;
      int ic = rem & 31, r = rem >> 5;
      int iy = oy - 1 + r;
      int ix = px0 - 1 + xi;
      float v = 0.f;
      if (iy >= 0 && iy < HW_ && ix >= 0 && ix < HW_)
        v = in[((size_t)(kT * 32 + ic) * HW_ + iy) * HW_ + ix];
      _Float16 hi = (_Float16)v;
      ldsH[(r * 20 + xi) * 40 + ic] = hi;
      ldsL[(r * 20 + xi) * 40 + ic] = (_Float16)(v - (float)hi);
    }
    __syncthreads();
#pragma unroll
    for (int ky = 0; ky < 3; ++ky) {
#pragma unroll
      for (int kx = 0; kx < 3; ++kx) {
        int tap = ky * 3 + kx;
        half8 AH = wh8[(((tap)*OCt + ocT) * ktiles + kT) * 64 + l];
        half8 AL = wh8[(((9 + tap) * OCt + ocT) * ktiles + kT) * 64 + l];
        half8 BH = *reinterpret_cast<const half8*>(&ldsH[(ky * 20 + n + kx) * 40 + koff]);
        half8 BL = *reinterpret_cast<const half8*>(&ldsL[(ky * 20 + n + kx) * 40 + koff]);
        acc = __builtin_amdgcn_mfma_f32_16x16x32_f16(AH, BH, acc, 0, 0, 0);
        acc = __builtin_amdgcn_mfma_f32_16x16x32_f16(AH, BL, acc, 0, 0, 0);
        acc = __builtin_amdgcn_mfma_f32_16x16x32_f16(AL, BH, acc, 0, 0, 0);
      }
    }
  }
  int oc0 = ocT * 16 + ((l >> 4) << 2);
  int ox = px0 + n;
#pragma unroll
  for (int r = 0; r < 4; ++r) {
    int oc = oc0 + r;
    float bv = bias[oc];
    size_t idx = ((size_t)oc * HW_ + oy) * HW_ + ox;
    float v32 = __fadd_rn(acc[r], bv);
    v32 = __fmul_rn(v32, kBNF);
    v32 = __fadd_rn(v32, skip[idx]);
    out[idx] = fmaxf(v32, 0.f);
  }
}

// ---------------------------------------------------------------- 1x1 conv, fp32 acc (R15)
template <int S, bool RELU>
__global__ __launch_bounds__(256) void conv1x1_k(
    const float* __restrict__ in, const float* __restrict__ w,
    const float* __restrict__ bias, float* __restrict__ out,
    int IC, int IH, int IW, int OC, int OH, int OW) {
  __shared__ float in_s[16][64];
  __shared__ float w_s[16][64];
  const int P = OH * OW;
  int t = threadIdx.x;
  int p0 = blockIdx.x * 64;
  int oc0 = blockIdx.y * 64;
  int oc4 = (t >> 4) * 4, px4 = (t & 15) * 4;
  float acc[4][4] = {};
  for (int ic0 = 0; ic0 < IC; ic0 += 16) {
    __syncthreads();
    {
      int e = t;
#pragma unroll
      for (int k = 0; k < 4; ++k, e += 256) {
        int icr = e >> 6, pxr = e & 63;
        int p = p0 + pxr;
        float v = 0.f;
        if (p < P) {
          int oy = p / OW, ox = p % OW;
          v = in[((ic0 + icr) * IH + oy * S) * IW + ox * S];
        }
        in_s[icr][pxr] = v;
      }
      e = t;
#pragma unroll
      for (int k = 0; k < 4; ++k, e += 256) {
        int icr = e >> 6, ocr = e & 63;
        w_s[icr][ocr] = w[(oc0 + ocr) * IC + ic0 + icr];
      }
    }
    __syncthreads();
#pragma unroll
    for (int icr = 0; icr < 16; ++icr) {
      float4 iv = *reinterpret_cast<const float4*>(&in_s[icr][px4]);
      float4 wv = *reinterpret_cast<const float4*>(&w_s[icr][oc4]);
      const float* ip = (const float*)&iv;
      const float* wp = (const float*)&wv;
#pragma unroll
      for (int o = 0; o < 4; ++o)
#pragma unroll
        for (int p = 0; p < 4; ++p)
          acc[o][p] = fmaf(wp[o], ip[p], acc[o][p]);
    }
  }
  int p = p0 + px4;
  if (p < P) {
    int oy = p / OW, ox = p % OW;
#pragma unroll
    for (int o = 0; o < 4; ++o) {
      int oc = oc0 + oc4 + o;
      float bv = bias[oc];
      float4 rv;
      float* rp = (float*)&rv;
#pragma unroll
      for (int pp = 0; pp < 4; ++pp) {
        float v32 = __fadd_rn(acc[o][pp], bv);
        v32 = __fmul_rn(v32, kBNF);
        if (RELU) v32 = fmaxf(v32, 0.f);
        rp[pp] = v32;
      }
      *reinterpret_cast<float4*>(&out[((size_t)oc * OH + oy) * OW + ox]) = rv;
    }
  }
}

// ---------------------------------------------------------------- ConvT weight prep -> bf16 A-fragments (R14)
__global__ __launch_bounds__(256) void prep_wb_k(const float* __restrict__ w,
                                                 __hip_bfloat16* __restrict__ wb,
                                                 int IC, int OC) {
  int i = blockIdx.x * 256 + threadIdx.x;
  int total = 16 * IC * OC;
  if (i >= total) return;
  int per_cfg = IC * OC;
  int cfg = i / per_cfg;
  int r = i - cfg * per_cfg;
  int ktiles = IC >> 5;
  int ocT = r / (ktiles * 512);
  int r2 = r - ocT * (ktiles * 512);
  int kT = r2 >> 9;
  int f = r2 & 511;
  int lane = f >> 3, e = f & 7;
  int m = lane & 15, kk = ((lane >> 4) << 3) + e;
  int oc = ocT * 16 + m, ic = kT * 32 + kk;
  int kyb = cfg >> 3, ty = (cfg >> 2) & 1, kx = cfg & 3;
  int ky = kyb + 2 * ty;
  wb[i] = __float2bfloat16(w[((size_t)ic * OC + oc) * 16 + ky * 4 + kx]);
}

// ---------------------------------------------------------------- ConvT k4 s2 p1 via MFMA bf16 (R14, validated)
__global__ __launch_bounds__(256) void convt_mfma_k(
    const float* __restrict__ in, const __hip_bfloat16* __restrict__ wb,
    const float* __restrict__ bias, float* __restrict__ out,
    int IC, int IH, int IW, int OC, int OH, int OW) {
  __shared__ __align__(16) __hip_bfloat16 lds[2 * 18 * 40];
  int t = threadIdx.x;
  int wv = t >> 6, l = t & 63;
  int ox0 = blockIdx.x * 32;
  int oy = blockIdx.y;
  int oc0w = blockIdx.z * 64 + wv * 16;
  int kyb = (oy & 1) ? 0 : 1;
  int hb = ox0 >> 1;
  int iy0n = oy + 1 - kyb;
  int iy0 = iy0n >> 1;
  bool ok0 = (iy0 < IH);
  int iy1n = oy + 1 - kyb - 2;
  int iy1 = iy1n >> 1;
  bool ok1 = (iy1n >= 0) && (iy1 < IH);
  f32x4 accE = {0.f, 0.f, 0.f, 0.f};
  f32x4 accO = {0.f, 0.f, 0.f, 0.f};
  const int ktiles = IC >> 5;
  int n = l & 15, koff = (l >> 4) * 8;
  const short8* wb8 = reinterpret_cast<const short8*>(wb);
  int ocT = oc0w >> 4;
  const int OCt = OC >> 4;
  for (int kT = 0; kT < ktiles; ++kT) {
    __syncthreads();
    for (int e = t; e < 1152; e += 256) {
      int ic = e / 36;
      int r = e - ic * 36;
      int ty = r / 18, xi = r - ty * 18;
      int ix = hb - 1 + xi;
      int iy = ty ? iy1 : iy0;
      bool ok = ty ? ok1 : ok0;
      float v = 0.f;
      if (ok && ix >= 0 && ix < IW)
        v = in[((size_t)(kT * 32 + ic) * IH + iy) * IW + ix];
      lds[(ty * 18 + xi) * 40 + ic] = __float2bfloat16(v);
    }
    __syncthreads();
#pragma unroll
    for (int ty = 0; ty < 2; ++ty) {
      short8 A0 = wb8[((((kyb * 2 + ty) * 4 + 0) * OCt + ocT) * ktiles + kT) * 64 + l];
      short8 A1 = wb8[((((kyb * 2 + ty) * 4 + 1) * OCt + ocT) * ktiles + kT) * 64 + l];
      short8 A2 = wb8[((((kyb * 2 + ty) * 4 + 2) * OCt + ocT) * ktiles + kT) * 64 + l];
      short8 A3 = wb8[((((kyb * 2 + ty) * 4 + 3) * OCt + ocT) * ktiles + kT) * 64 + l];
      short8 b0 = *reinterpret_cast<const short8*>(&lds[(ty * 18 + 0 + n) * 40 + koff]);
      short8 b1 = *reinterpret_cast<const short8*>(&lds[(ty * 18 + 1 + n) * 40 + koff]);
      short8 b2 = *reinterpret_cast<const short8*>(&lds[(ty * 18 + 2 + n) * 40 + koff]);
      accE = __builtin_amdgcn_mfma_f32_16x16x32_bf16(A1, b1, accE, 0, 0, 0);
      accE = __builtin_amdgcn_mfma_f32_16x16x32_bf16(A3, b0, accE, 0, 0, 0);
      accO = __builtin_amdgcn_mfma_f32_16x16x32_bf16(A0, b2, accO, 0, 0, 0);
      accO = __builtin_amdgcn_mfma_f32_16x16x32_bf16(A2, b1, accO, 0, 0, 0);
    }
  }
  int ocr0 = oc0w + ((l >> 4) << 2);
  int oxE = ox0 + 2 * n;
  int oxO = ox0 + 1 + 2 * n;
#pragma unroll
  for (int r = 0; r < 4; ++r) {
    float bv = bias[ocr0 + r];
    size_t rowbase = ((size_t)(ocr0 + r) * OH + oy) * OW;
    out[rowbase + oxE] = fmaxf((accE[r] + bv) * kBNF, 0.f);
    out[rowbase + oxO] = fmaxf((accO[r] + bv) * kBNF, 0.f);
  }
}

// ---------------------------------------------------------------- final 3x3 conv 128->1 + sigmoid (R9)
__global__ __launch_bounds__(320) void dow_k(const float* __restrict__ in,
                                             const float* __restrict__ w,
                                             const float* __restrict__ bias,
                                             float* __restrict__ out) {
  const int H = 320, W = 320, IC = 128;
  int oy = blockIdx.x;
  int tx = threadIdx.x;
  __shared__ float in_s[4][3][W + 2];
  __shared__ float w_s[IC * 9];
  for (int e = tx; e < IC * 9; e += 320) w_s[e] = w[e];
  float acc = 0.f;
  for (int ic0 = 0; ic0 < IC; ic0 += 4) {
    __syncthreads();
    for (int e = tx; e < 4 * 3 * (W + 2); e += 320) {
      int icr = e / (3 * (W + 2));
      int rem = e - icr * (3 * (W + 2));
      int r = rem / (W + 2), c = rem - r * (W + 2);
      int iy = oy + r - 1, ix = c - 1;
      float v = 0.f;
      if (iy >= 0 && iy < H && ix >= 0 && ix < W)
        v = in[((ic0 + icr) * H + iy) * W + ix];
      in_s[icr][r][c] = v;
    }
    __syncthreads();
#pragma unroll
    for (int icr = 0; icr < 4; ++icr)
#pragma unroll
      for (int r = 0; r < 3; ++r)
#pragma unroll
        for (int c = 0; c < 3; ++c)
          acc = fmaf(w_s[(ic0 + icr) * 9 + r * 3 + c], in_s[icr][r][tx + c], acc);
  }
  acc += bias[0];
  out[oy * W + tx] = 1.f / (1.f + expf(-acc));
}

// ---------------------------------------------------------------- codebook sq-norms: numpy-pairwise fp32
__global__ __launch_bounds__(256) void cbprep_np(const float* __restrict__ cb,
                                                 float* __restrict__ c2f) {
  int e = blockIdx.x, t = threadIdx.x;
  __shared__ float a[256];
  a[t] = cb[e * 256 + t];
  __syncthreads();
  if (t == 0) {
    float tot = 0.f;
    for (int h = 0; h < 2; ++h) {
      const float* p = a + h * 128;
      float r[8];
#pragma unroll
      for (int j = 0; j < 8; ++j) r[j] = __fmul_rn(p[j], p[j]);
      for (int i = 8; i < 128; i += 8)
#pragma unroll
        for (int j = 0; j < 8; ++j) r[j] = __fadd_rn(r[j], __fmul_rn(p[i + j], p[i + j]));
      float s = __fadd_rn(__fadd_rn(__fadd_rn(r[0], r[1]), __fadd_rn(r[2], r[3])),
                          __fadd_rn(__fadd_rn(r[4], r[5]), __fadd_rn(r[6], r[7])));
      tot = (h == 0) ? s : __fadd_rn(tot, s);
    }
    c2f[e] = tot;
  }
}

// ---------------------------------------------------------------- VQ: 4 rows/block (R15, validated)
__global__ __launch_bounds__(256) void vq_ref_k(const float* __restrict__ z,
                                                const float* __restrict__ cb,
                                                const float* __restrict__ c2f,
                                                float* __restrict__ zq_out,
                                                float* __restrict__ idx_out) {
  int n0 = blockIdx.x * 4;
  int t = threadIdx.x;
  __shared__ float f[4][256];
  __shared__ float dist[4][1024];
  __shared__ float rr[4][2][8];
  __shared__ float f2s[4];
  __shared__ int bestIdx[4];
  for (int e = t; e < 1024; e += 256) {
    int r = e >> 8, c = e & 255;
    f[r][c] = z[(size_t)(n0 + r) * 256 + c];
  }
  __syncthreads();
  if (t < 64) {
    int row = t >> 4, hh = (t >> 3) & 1, j = t & 7;
    const float* p = f[row] + hh * 128;
    float r = __fmul_rn(p[j], p[j]);
    for (int i = 8; i < 128; i += 8) r = __fadd_rn(r, __fmul_rn(p[i + j], p[i + j]));
    rr[row][hh][j] = r;
  }
  __syncthreads();
  if (t < 4) {
    float s0 = __fadd_rn(__fadd_rn(__fadd_rn(rr[t][0][0], rr[t][0][1]), __fadd_rn(rr[t][0][2], rr[t][0][3])),
                         __fadd_rn(__fadd_rn(rr[t][0][4], rr[t][0][5]), __fadd_rn(rr[t][0][6], rr[t][0][7])));
    float s1 = __fadd_rn(__fadd_rn(__fadd_rn(rr[t][1][0], rr[t][1][1]), __fadd_rn(rr[t][1][2], rr[t][1][3])),
                         __fadd_rn(__fadd_rn(rr[t][1][4], rr[t][1][5]), __fadd_rn(rr[t][1][6], rr[t][1][7])));
    f2s[t] = __fadd_rn(s0, s1);
  }
  __syncthreads();
  for (int e = t; e < 1024; e += 256) {
    const float4* cbe = reinterpret_cast<const float4*>(cb + (size_t)e * 256);
    double d0 = 0.0, d1 = 0.0, d2 = 0.0, d3 = 0.0;
    for (int d = 0; d < 64; ++d) {
      float4 c4 = cbe[d];
      float4 f0 = *reinterpret_cast<const float4*>(&f[0][d * 4]);
      float4 f1 = *reinterpret_cast<const float4*>(&f[1][d * 4]);
      float4 f2v = *reinterpret_cast<const float4*>(&f[2][d * 4]);
      float4 f3 = *reinterpret_cast<const float4*>(&f[3][d * 4]);
      d0 = fma((double)f0.x, (double)c4.x, d0); d0 = fma((double)f0.y, (double)c4.y, d0);
      d0 = fma((double)f0.z, (double)c4.z, d0); d0 = fma((double)f0.w, (double)c4.w, d0);
      d1 = fma((double)f1.x, (double)c4.x, d1); d1 = fma((double)f1.y, (double)c4.y, d1);
      d1 = fma((double)f1.z, (double)c4.z, d1); d1 = fma((double)f1.w, (double)c4.w, d1);
      d2 = fma((double)f2v.x, (double)c4.x, d2); d2 = fma((double)f2v.y, (double)c4.y, d2);
      d2 = fma((double)f2v.z, (double)c4.z, d2); d2 = fma((double)f2v.w, (double)c4.w, d2);
      d3 = fma((double)f3.x, (double)c4.x, d3); d3 = fma((double)f3.y, (double)c4.y, d3);
      d3 = fma((double)f3.z, (double)c4.z, d3); d3 = fma((double)f3.w, (double)c4.w, d3);
    }
    float c2e = c2f[e];
    dist[0][e] = __fsub_rn(__fadd_rn(f2s[0], c2e), __fmul_rn(2.f, (float)d0));
    dist[1][e] = __fsub_rn(__fadd_rn(f2s[1], c2e), __fmul_rn(2.f, (float)d1));
    dist[2][e] = __fsub_rn(__fadd_rn(f2s[2], c2e), __fmul_rn(2.f, (float)d2));
    dist[3][e] = __fsub_rn(__fadd_rn(f2s[3], c2e), __fmul_rn(2.f, (float)d3));
  }
  __syncthreads();
  {
    int row = t >> 6, l = t & 63;
    float bv = dist[row][l];
    int bi = l;
    for (int e = l + 64; e < 1024; e += 64) {
      float v = dist[row][e];
      if (v < bv) { bv = v; bi = e; }
    }
#pragma unroll
    for (int m = 1; m < 64; m <<= 1) {
      float ov = __shfl_xor(bv, m, 64);
      int oi = __shfl_xor(bi, m, 64);
      if (ov < bv || (ov == bv && oi < bi)) { bv = ov; bi = oi; }
    }
    if (l == 0) {
      bestIdx[row] = bi;
      idx_out[n0 + row] = (float)bi;
    }
  }
  __syncthreads();
#pragma unroll
  for (int r = 0; r < 4; ++r)
    zq_out[(size_t)(n0 + r) * 256 + t] = cb[(size_t)bestIdx[r] * 256 + t];
}

// ================================================================ host
extern "C" void kernel_launch(void* const* d_in, const int* in_sizes, int n_in,
                              void* d_out, int out_size, void* d_ws, size_t ws_size,
                              hipStream_t stream) {
  const float* x = (const float*)d_in[0];
  const float* w0 = (const float*)d_in[1];
  const float* b0 = (const float*)d_in[2];
  const float* a_c1w = (const float*)d_in[3];
  const float* a_c1b = (const float*)d_in[4];
  const float* a_c2w = (const float*)d_in[5];
  const float* a_c2b = (const float*)d_in[6];
  const float* a_scw = (const float*)d_in[7];
  const float* a_scb = (const float*)d_in[8];
  const float* b_c1w = (const float*)d_in[9];
  const float* b_c1b = (const float*)d_in[10];
  const float* b_c2w = (const float*)d_in[11];
  const float* b_c2b = (const float*)d_in[12];
  const float* b_scw = (const float*)d_in[13];
  const float* b_scb = (const float*)d_in[14];
  const float* ew = (const float*)d_in[15];
  const float* eb = (const float*)d_in[16];
  const float* cb = (const float*)d_in[17];
  const float* d0w = (const float*)d_in[18];
  const float* d0b = (const float*)d_in[19];
  const float* dt1w = (const float*)d_in[20];
  const float* dt1b = (const float*)d_in[21];
  const float* dt2w = (const float*)d_in[22];
  const float* dt2b = (const float*)d_in[23];
  const float* doww = (const float*)d_in[24];
  const float* dob = (const float*)d_in[25];

  // ws (floats): A 13.1M | B 6.55M | C 6.55M | c2f 1024  ~= 105 MB (unchanged)
  float* ws = (float*)d_ws;
  float* A = ws;
  float* Bf = ws + 13107200;
  float* Cf = ws + 19660800;
  float* c2f = ws + 26214400;
  float* w3_ac1 = Cf;                                   // 294,912 f (fp32, S=2)
  float* w3_bc1 = Bf + 3300000;                         // 1,179,648 f (fp32, S=2)
  // fp16-split A-frags for S=1 convs (same byte size as R16's bf16 buffers):
  _Float16* wh_ac2 = (_Float16*)(void*)(A + 6600000);   // 1,179,648 f16 = 589,824 f
  _Float16* wh_bc2 = (_Float16*)(void*)(A + 3300000);   // 4,718,592 f16 = 2,359,296 f
  __hip_bfloat16* wb_dt1 = (__hip_bfloat16*)(void*)A;
  __hip_bfloat16* wb_dt2 = (__hip_bfloat16*)(void*)(Bf + 3400000);

  float* outf = (float*)d_out;
  float* recon = outf;
  float* zq = outf + 409600;
  float* idxo = zq + 6553600;

  cbprep_np<<<1024, 256, 0, stream>>>(cb, c2f);

  for (int b = 0; b < 4; ++b) {
    const float* xb = x + (size_t)b * 102400;
    float* zqb = zq + (size_t)b * 1638400;
    float* idxb = idxo + (size_t)b * 6400;
    float* reconb = recon + (size_t)b * 102400;

    // encoder
    conv0_k<<<320, 320, 0, stream>>>(xb, w0, b0, A);
    prep_w3_k<<<1152, 256, 0, stream>>>(a_c1w, w3_ac1, 128, 256);
    conv3x3_k<2, true, false><<<dim3(2, 160, 4), 320, 0, stream>>>(
        A, w3_ac1, a_c1b, nullptr, Bf, 128, 320, 320, 256, 160, 160);
    conv1x1_k<2, false><<<dim3(400, 4), 256, 0, stream>>>(
        A, a_scw, a_scb, Cf, 128, 320, 320, 256, 160, 160);
    prep_w3h_k<<<4608, 256, 0, stream>>>(a_c2w, wh_ac2, 256, 256);   // 1,179,648 el
    conv3s1_mfma_k<<<dim3(10, 160, 4), 256, 0, stream>>>(
        Bf, wh_ac2, a_c2b, Cf, A, 256, 160, 256);
    prep_w3_k<<<4608, 256, 0, stream>>>(b_c1w, w3_bc1, 256, 512);
    conv3x3_k<2, true, false><<<dim3(1, 80, 8), 320, 0, stream>>>(
        A, w3_bc1, b_c1b, nullptr, Bf, 256, 160, 160, 512, 80, 80);
    conv1x1_k<2, false><<<dim3(100, 8), 256, 0, stream>>>(
        A, b_scw, b_scb, Cf, 256, 160, 160, 512, 80, 80);
    prep_w3h_k<<<18432, 256, 0, stream>>>(b_c2w, wh_bc2, 512, 512);  // 4,718,592 el
    conv3s1_mfma_k<<<dim3(5, 80, 8), 256, 0, stream>>>(
        Bf, wh_bc2, b_c2b, Cf, A, 512, 80, 512);
    conv1x1_k<1, false><<<dim3(100, 4), 256, 0, stream>>>(
        A, ew, eb, Cf, 512, 80, 80, 256, 80, 80);
    // VQ
    vq_ref_k<<<1600, 256, 0, stream>>>(Cf, cb, c2f, zqb, idxb);
    // decoder: bf16 MFMA ConvT (R14)
    prep_wb_k<<<8192, 256, 0, stream>>>(dt1w, wb_dt1, 512, 256);
    prep_wb_k<<<2048, 256, 0, stream>>>(dt2w, wb_dt2, 256, 128);
    conv1x1_k<1, true><<<dim3(100, 8), 256, 0, stream>>>(
        zqb, d0w, d0b, Bf, 256, 80, 80, 512, 80, 80);
    convt_mfma_k<<<dim3(5, 160, 4), 256, 0, stream>>>(
        Bf, wb_dt1, dt1b, Cf, 512, 80, 80, 256, 160, 160);
    convt_mfma_k<<<dim3(10, 320, 2), 256, 0, stream>>>(
        Cf, wb_dt2, dt2b, A, 256, 160, 160, 128, 320, 320);
    dow_k<<<320, 320, 0, stream>>>(A, doww, dob, reconb);
  }
}

// Round 19
// 6906.615 us; speedup vs baseline: 3.0043x; 1.5008x over previous
//
#include <hip/hip_runtime.h>
#include <hip/hip_bf16.h>
#include <math.h>

// Round 19 (= intended R18, resubmitted complete): S=2 encoder convs (a_c1,
// b_c1) -> fp16-split MFMA (scheme validated flip-free in R17 on a_c2/b_c2).
// Stride-2 via parity-split LDS: Even/Odd col arrays; tap kx reads
// Even[n] / Odd[n] / Even[n+1]. Everything else R17 verbatim.
// Diagnostic: absmax == 3.814697e-06 iff zero argmin flips.

static constexpr float kBNF = 0.9999950000374997f;

typedef short short8 __attribute__((ext_vector_type(8)));
typedef _Float16 half8 __attribute__((ext_vector_type(8)));
typedef float f32x4 __attribute__((ext_vector_type(4)));

// ---------------------------------------------------------------- conv0: 1->128, 3x3, s1, relu (B=1), fp32
__global__ __launch_bounds__(320) void conv0_k(const float* __restrict__ x,
                                               const float* __restrict__ w,
                                               const float* __restrict__ b,
                                               float* __restrict__ out) {
  const int H = 320, W = 320, OC = 128;
  int oy = blockIdx.x;
  int tx = threadIdx.x;
  __shared__ float in_s[3][W + 2];
  __shared__ float w_s[128 * 9];
  __shared__ float b_s[128];
  for (int e = tx; e < 3 * (W + 2); e += 320) {
    int r = e / (W + 2), c = e % (W + 2);
    int iy = oy + r - 1, ix = c - 1;
    float v = 0.f;
    if (iy >= 0 && iy < H && ix >= 0 && ix < W) v = x[iy * W + ix];
    in_s[r][c] = v;
  }
  for (int e = tx; e < 128 * 9; e += 320) w_s[e] = w[e];
  for (int e = tx; e < 128; e += 320) b_s[e] = b[e];
  __syncthreads();
  float iv[9];
#pragma unroll
  for (int r = 0; r < 3; ++r)
#pragma unroll
    for (int c = 0; c < 3; ++c) iv[r * 3 + c] = in_s[r][tx + c];
  for (int oc = 0; oc < OC; ++oc) {
    float acc = 0.f;
#pragma unroll
    for (int t = 0; t < 9; ++t) acc = fmaf(w_s[oc * 9 + t], iv[t], acc);
    float v32 = __fadd_rn(acc, b_s[oc]);
    v32 = __fmul_rn(v32, kBNF);
    out[(oc * H + oy) * W + tx] = fmaxf(v32, 0.f);
  }
}

// ---------------------------------------------------------------- conv3x3 weight prep -> fp16-split A-frags
// layout: ((((split*9+tap)*(OC/16)+ocT)*(IC/32)+kT)*64+lane)*8+e  (OIHW src)
__global__ __launch_bounds__(256) void prep_w3h_k(const float* __restrict__ w,
                                                  _Float16* __restrict__ wh,
                                                  int IC, int OC) {
  int i = blockIdx.x * 256 + threadIdx.x;
  int total = 2 * 9 * IC * OC;
  if (i >= total) return;
  int e = i & 7;
  int lane = (i >> 3) & 63;
  int rest = i >> 9;
  int ktiles = IC >> 5;
  int kT = rest % ktiles;
  int rest2 = rest / ktiles;
  int OCt = OC >> 4;
  int ocT = rest2 % OCt;
  int rest3 = rest2 / OCt;
  int tap = rest3 % 9;
  int split = rest3 / 9;
  int m = lane & 15, k = ((lane >> 4) << 3) + e;
  int oc = ocT * 16 + m, ic = kT * 32 + k;
  float v = w[((size_t)oc * IC + ic) * 9 + tap];
  _Float16 hi = (_Float16)v;
  wh[i] = (split == 0) ? hi : (_Float16)(v - (float)hi);
}

// ---------------------------------------------------------------- 3x3 conv S=1 via MFMA fp16-split (R17, validated)
__global__ __launch_bounds__(256) void conv3s1_mfma_k(
    const float* __restrict__ in, const _Float16* __restrict__ wh,
    const float* __restrict__ bias, const float* __restrict__ skip,
    float* __restrict__ out, int IC, int HW_, int OC) {
  __shared__ __align__(16) _Float16 ldsH[3 * 20 * 40];
  __shared__ __align__(16) _Float16 ldsL[3 * 20 * 40];
  int t = threadIdx.x;
  int wv = t >> 6, l = t & 63;
  int px0 = blockIdx.x * 16;
  int oy = blockIdx.y;
  int ocT = blockIdx.z * 4 + wv;
  const int ktiles = IC >> 5;
  const int OCt = OC >> 4;
  int n = l & 15, koff = (l >> 4) * 8;
  f32x4 acc = {0.f, 0.f, 0.f, 0.f};
  const half8* wh8 = reinterpret_cast<const half8*>(wh);
  for (int kT = 0; kT < ktiles; ++kT) {
    __syncthreads();
    for (int e = t; e < 1728; e += 256) {
      int xi = e % 18;
      int rem = e / 18;
      int ic = rem & 31, r = rem >> 5;
      int iy = oy - 1 + r;
      int ix = px0 - 1 + xi;
      float v = 0.f;
      if (iy >= 0 && iy < HW_ && ix >= 0 && ix < HW_)
        v = in[((size_t)(kT * 32 + ic) * HW_ + iy) * HW_ + ix];
      _Float16 hi = (_Float16)v;
      ldsH[(r * 20 + xi) * 40 + ic] = hi;
      ldsL[(r * 20 + xi) * 40 + ic] = (_Float16)(v - (float)hi);
    }
    __syncthreads();
#pragma unroll
    for (int ky = 0; ky < 3; ++ky) {
#pragma unroll
      for (int kx = 0; kx < 3; ++kx) {
        int tap = ky * 3 + kx;
        half8 AH = wh8[(((tap)*OCt + ocT) * ktiles + kT) * 64 + l];
        half8 AL = wh8[(((9 + tap) * OCt + ocT) * ktiles + kT) * 64 + l];
        half8 BH = *reinterpret_cast<const half8*>(&ldsH[(ky * 20 + n + kx) * 40 + koff]);
        half8 BL = *reinterpret_cast<const half8*>(&ldsL[(ky * 20 + n + kx) * 40 + koff]);
        acc = __builtin_amdgcn_mfma_f32_16x16x32_f16(AH, BH, acc, 0, 0, 0);
        acc = __builtin_amdgcn_mfma_f32_16x16x32_f16(AH, BL, acc, 0, 0, 0);
        acc = __builtin_amdgcn_mfma_f32_16x16x32_f16(AL, BH, acc, 0, 0, 0);
      }
    }
  }
  int oc0 = ocT * 16 + ((l >> 4) << 2);
  int ox = px0 + n;
#pragma unroll
  for (int r = 0; r < 4; ++r) {
    int oc = oc0 + r;
    float bv = bias[oc];
    size_t idx = ((size_t)oc * HW_ + oy) * HW_ + ox;
    float v32 = __fadd_rn(acc[r], bv);
    v32 = __fmul_rn(v32, kBNF);
    v32 = __fadd_rn(v32, skip[idx]);
    out[idx] = fmaxf(v32, 0.f);
  }
}

// ---------------------------------------------------------------- 3x3 conv S=2 via MFMA fp16-split (parity LDS)
// ix = 2*(px0+n)+kx-1; rel xi = 2n+kx: kx=0 -> E[n], kx=1 -> O[n], kx=2 -> E[n+1]
__global__ __launch_bounds__(256) void conv3s2_mfma_k(
    const float* __restrict__ in, const _Float16* __restrict__ wh,
    const float* __restrict__ bias, float* __restrict__ out,
    int IC, int IH, int IW, int OC, int OH, int OW) {
  __shared__ __align__(16) _Float16 ldsEH[3 * 17 * 40];
  __shared__ __align__(16) _Float16 ldsEL[3 * 17 * 40];
  __shared__ __align__(16) _Float16 ldsOH[3 * 16 * 40];
  __shared__ __align__(16) _Float16 ldsOL[3 * 16 * 40];
  int t = threadIdx.x;
  int wv = t >> 6, l = t & 63;
  int px0 = blockIdx.x * 16;
  int oy = blockIdx.y;
  int ocT = blockIdx.z * 4 + wv;
  const int ktiles = IC >> 5;
  const int OCt = OC >> 4;
  int n = l & 15, koff = (l >> 4) * 8;
  f32x4 acc = {0.f, 0.f, 0.f, 0.f};
  const half8* wh8 = reinterpret_cast<const half8*>(wh);
  for (int kT = 0; kT < ktiles; ++kT) {
    __syncthreads();
    for (int e = t; e < 3168; e += 256) {  // 3 ky * 33 xi * 32 ic
      int ic = e & 31;
      int rem = e >> 5;
      int xi = rem % 33, ky = rem / 33;
      int iy = oy * 2 - 1 + ky;
      int ix = px0 * 2 - 1 + xi;
      float v = 0.f;
      if (iy >= 0 && iy < IH && ix >= 0 && ix < IW)
        v = in[((size_t)(kT * 32 + ic) * IH + iy) * IW + ix];
      _Float16 hi = (_Float16)v;
      _Float16 lo = (_Float16)(v - (float)hi);
      int hrow = xi >> 1;
      if (xi & 1) {
        ldsOH[(ky * 16 + hrow) * 40 + ic] = hi;
        ldsOL[(ky * 16 + hrow) * 40 + ic] = lo;
      } else {
        ldsEH[(ky * 17 + hrow) * 40 + ic] = hi;
        ldsEL[(ky * 17 + hrow) * 40 + ic] = lo;
      }
    }
    __syncthreads();
#pragma unroll
    for (int ky = 0; ky < 3; ++ky) {
#pragma unroll
      for (int kx = 0; kx < 3; ++kx) {
        int tap = ky * 3 + kx;
        half8 AH = wh8[(((tap)*OCt + ocT) * ktiles + kT) * 64 + l];
        half8 AL = wh8[(((9 + tap) * OCt + ocT) * ktiles + kT) * 64 + l];
        half8 BH, BL;
        if (kx == 0) {
          BH = *reinterpret_cast<const half8*>(&ldsEH[(ky * 17 + n) * 40 + koff]);
          BL = *reinterpret_cast<const half8*>(&ldsEL[(ky * 17 + n) * 40 + koff]);
        } else if (kx == 1) {
          BH = *reinterpret_cast<const half8*>(&ldsOH[(ky * 16 + n) * 40 + koff]);
          BL = *reinterpret_cast<const half8*>(&ldsOL[(ky * 16 + n) * 40 + koff]);
        } else {
          BH = *reinterpret_cast<const half8*>(&ldsEH[(ky * 17 + n + 1) * 40 + koff]);
          BL = *reinterpret_cast<const half8*>(&ldsEL[(ky * 17 + n + 1) * 40 + koff]);
        }
        acc = __builtin_amdgcn_mfma_f32_16x16x32_f16(AH, BH, acc, 0, 0, 0);
        acc = __builtin_amdgcn_mfma_f32_16x16x32_f16(AH, BL, acc, 0, 0, 0);
        acc = __builtin_amdgcn_mfma_f32_16x16x32_f16(AL, BH, acc, 0, 0, 0);
      }
    }
  }
  int oc0 = ocT * 16 + ((l >> 4) << 2);
  int ox = px0 + n;
#pragma unroll
  for (int r = 0; r < 4; ++r) {
    int oc = oc0 + r;
    float bv = bias[oc];
    size_t idx = ((size_t)oc * OH + oy) * OW + ox;
    float v32 = __fadd_rn(acc[r], bv);
    v32 = __fmul_rn(v32, kBNF);
    out[idx] = fmaxf(v32, 0.f);
  }
}

// ---------------------------------------------------------------- 1x1 conv, fp32 acc (R15)
template <int S, bool RELU>
__global__ __launch_bounds__(256) void conv1x1_k(
    const float* __restrict__ in, const float* __restrict__ w,
    const float* __restrict__ bias, float* __restrict__ out,
    int IC, int IH, int IW, int OC, int OH, int OW) {
  __shared__ float in_s[16][64];
  __shared__ float w_s[16][64];
  const int P = OH * OW;
  int t = threadIdx.x;
  int p0 = blockIdx.x * 64;
  int oc0 = blockIdx.y * 64;
  int oc4 = (t >> 4) * 4, px4 = (t & 15) * 4;
  float acc[4][4] = {};
  for (int ic0 = 0; ic0 < IC; ic0 += 16) {
    __syncthreads();
    {
      int e = t;
#pragma unroll
      for (int k = 0; k < 4; ++k, e += 256) {
        int icr = e >> 6, pxr = e & 63;
        int p = p0 + pxr;
        float v = 0.f;
        if (p < P) {
          int oy = p / OW, ox = p % OW;
          v = in[((ic0 + icr) * IH + oy * S) * IW + ox * S];
        }
        in_s[icr][pxr] = v;
      }
      e = t;
#pragma unroll
      for (int k = 0; k < 4; ++k, e += 256) {
        int icr = e >> 6, ocr = e & 63;
        w_s[icr][ocr] = w[(oc0 + ocr) * IC + ic0 + icr];
      }
    }
    __syncthreads();
#pragma unroll
    for (int icr = 0; icr < 16; ++icr) {
      float4 iv = *reinterpret_cast<const float4*>(&in_s[icr][px4]);
      float4 wv = *reinterpret_cast<const float4*>(&w_s[icr][oc4]);
      const float* ip = (const float*)&iv;
      const float* wp = (const float*)&wv;
#pragma unroll
      for (int o = 0; o < 4; ++o)
#pragma unroll
        for (int p = 0; p < 4; ++p)
          acc[o][p] = fmaf(wp[o], ip[p], acc[o][p]);
    }
  }
  int p = p0 + px4;
  if (p < P) {
    int oy = p / OW, ox = p % OW;
#pragma unroll
    for (int o = 0; o < 4; ++o) {
      int oc = oc0 + oc4 + o;
      float bv = bias[oc];
      float4 rv;
      float* rp = (float*)&rv;
#pragma unroll
      for (int pp = 0; pp < 4; ++pp) {
        float v32 = __fadd_rn(acc[o][pp], bv);
        v32 = __fmul_rn(v32, kBNF);
        if (RELU) v32 = fmaxf(v32, 0.f);
        rp[pp] = v32;
      }
      *reinterpret_cast<float4*>(&out[((size_t)oc * OH + oy) * OW + ox]) = rv;
    }
  }
}

// ---------------------------------------------------------------- ConvT weight prep -> bf16 A-fragments (R14)
__global__ __launch_bounds__(256) void prep_wb_k(const float* __restrict__ w,
                                                 __hip_bfloat16* __restrict__ wb,
                                                 int IC, int OC) {
  int i = blockIdx.x * 256 + threadIdx.x;
  int total = 16 * IC * OC;
  if (i >= total) return;
  int per_cfg = IC * OC;
  int cfg = i / per_cfg;
  int r = i - cfg * per_cfg;
  int ktiles = IC >> 5;
  int ocT = r / (ktiles * 512);
  int r2 = r - ocT * (ktiles * 512);
  int kT = r2 >> 9;
  int f = r2 & 511;
  int lane = f >> 3, e = f & 7;
  int m = lane & 15, kk = ((lane >> 4) << 3) + e;
  int oc = ocT * 16 + m, ic = kT * 32 + kk;
  int kyb = cfg >> 3, ty = (cfg >> 2) & 1, kx = cfg & 3;
  int ky = kyb + 2 * ty;
  wb[i] = __float2bfloat16(w[((size_t)ic * OC + oc) * 16 + ky * 4 + kx]);
}

// ---------------------------------------------------------------- ConvT k4 s2 p1 via MFMA bf16 (R14, validated)
__global__ __launch_bounds__(256) void convt_mfma_k(
    const float* __restrict__ in, const __hip_bfloat16* __restrict__ wb,
    const float* __restrict__ bias, float* __restrict__ out,
    int IC, int IH, int IW, int OC, int OH, int OW) {
  __shared__ __align__(16) __hip_bfloat16 lds[2 * 18 * 40];
  int t = threadIdx.x;
  int wv = t >> 6, l = t & 63;
  int ox0 = blockIdx.x * 32;
  int oy = blockIdx.y;
  int oc0w = blockIdx.z * 64 + wv * 16;
  int kyb = (oy & 1) ? 0 : 1;
  int hb = ox0 >> 1;
  int iy0n = oy + 1 - kyb;
  int iy0 = iy0n >> 1;
  bool ok0 = (iy0 < IH);
  int iy1n = oy + 1 - kyb - 2;
  int iy1 = iy1n >> 1;
  bool ok1 = (iy1n >= 0) && (iy1 < IH);
  f32x4 accE = {0.f, 0.f, 0.f, 0.f};
  f32x4 accO = {0.f, 0.f, 0.f, 0.f};
  const int ktiles = IC >> 5;
  int n = l & 15, koff = (l >> 4) * 8;
  const short8* wb8 = reinterpret_cast<const short8*>(wb);
  int ocT = oc0w >> 4;
  const int OCt = OC >> 4;
  for (int kT = 0; kT < ktiles; ++kT) {
    __syncthreads();
    for (int e = t; e < 1152; e += 256) {
      int ic = e / 36;
      int r = e - ic * 36;
      int ty = r / 18, xi = r - ty * 18;
      int ix = hb - 1 + xi;
      int iy = ty ? iy1 : iy0;
      bool ok = ty ? ok1 : ok0;
      float v = 0.f;
      if (ok && ix >= 0 && ix < IW)
        v = in[((size_t)(kT * 32 + ic) * IH + iy) * IW + ix];
      lds[(ty * 18 + xi) * 40 + ic] = __float2bfloat16(v);
    }
    __syncthreads();
#pragma unroll
    for (int ty = 0; ty < 2; ++ty) {
      short8 A0 = wb8[((((kyb * 2 + ty) * 4 + 0) * OCt + ocT) * ktiles + kT) * 64 + l];
      short8 A1 = wb8[((((kyb * 2 + ty) * 4 + 1) * OCt + ocT) * ktiles + kT) * 64 + l];
      short8 A2 = wb8[((((kyb * 2 + ty) * 4 + 2) * OCt + ocT) * ktiles + kT) * 64 + l];
      short8 A3 = wb8[((((kyb * 2 + ty) * 4 + 3) * OCt + ocT) * ktiles + kT) * 64 + l];
      short8 b0 = *reinterpret_cast<const short8*>(&lds[(ty * 18 + 0 + n) * 40 + koff]);
      short8 b1 = *reinterpret_cast<const short8*>(&lds[(ty * 18 + 1 + n) * 40 + koff]);
      short8 b2 = *reinterpret_cast<const short8*>(&lds[(ty * 18 + 2 + n) * 40 + koff]);
      accE = __builtin_amdgcn_mfma_f32_16x16x32_bf16(A1, b1, accE, 0, 0, 0);
      accE = __builtin_amdgcn_mfma_f32_16x16x32_bf16(A3, b0, accE, 0, 0, 0);
      accO = __builtin_amdgcn_mfma_f32_16x16x32_bf16(A0, b2, accO, 0, 0, 0);
      accO = __builtin_amdgcn_mfma_f32_16x16x32_bf16(A2, b1, accO, 0, 0, 0);
    }
  }
  int ocr0 = oc0w + ((l >> 4) << 2);
  int oxE = ox0 + 2 * n;
  int oxO = ox0 + 1 + 2 * n;
#pragma unroll
  for (int r = 0; r < 4; ++r) {
    float bv = bias[ocr0 + r];
    size_t rowbase = ((size_t)(ocr0 + r) * OH + oy) * OW;
    out[rowbase + oxE] = fmaxf((accE[r] + bv) * kBNF, 0.f);
    out[rowbase + oxO] = fmaxf((accO[r] + bv) * kBNF, 0.f);
  }
}

// ---------------------------------------------------------------- final 3x3 conv 128->1 + sigmoid (R9)
__global__ __launch_bounds__(320) void dow_k(const float* __restrict__ in,
                                             const float* __restrict__ w,
                                             const float* __restrict__ bias,
                                             float* __restrict__ out) {
  const int H = 320, W = 320, IC = 128;
  int oy = blockIdx.x;
  int tx = threadIdx.x;
  __shared__ float in_s[4][3][W + 2];
  __shared__ float w_s[IC * 9];
  for (int e = tx; e < IC * 9; e += 320) w_s[e] = w[e];
  float acc = 0.f;
  for (int ic0 = 0; ic0 < IC; ic0 += 4) {
    __syncthreads();
    for (int e = tx; e < 4 * 3 * (W + 2); e += 320) {
      int icr = e / (3 * (W + 2));
      int rem = e - icr * (3 * (W + 2));
      int r = rem / (W + 2), c = rem - r * (W + 2);
      int iy = oy + r - 1, ix = c - 1;
      float v = 0.f;
      if (iy >= 0 && iy < H && ix >= 0 && ix < W)
        v = in[((ic0 + icr) * H + iy) * W + ix];
      in_s[icr][r][c] = v;
    }
    __syncthreads();
#pragma unroll
    for (int icr = 0; icr < 4; ++icr)
#pragma unroll
      for (int r = 0; r < 3; ++r)
#pragma unroll
        for (int c = 0; c < 3; ++c)
          acc = fmaf(w_s[(ic0 + icr) * 9 + r * 3 + c], in_s[icr][r][tx + c], acc);
  }
  acc += bias[0];
  out[oy * W + tx] = 1.f / (1.f + expf(-acc));
}

// ---------------------------------------------------------------- codebook sq-norms: numpy-pairwise fp32
__global__ __launch_bounds__(256) void cbprep_np(const float* __restrict__ cb,
                                                 float* __restrict__ c2f) {
  int e = blockIdx.x, t = threadIdx.x;
  __shared__ float a[256];
  a[t] = cb[e * 256 + t];
  __syncthreads();
  if (t == 0) {
    float tot = 0.f;
    for (int h = 0; h < 2; ++h) {
      const float* p = a + h * 128;
      float r[8];
#pragma unroll
      for (int j = 0; j < 8; ++j) r[j] = __fmul_rn(p[j], p[j]);
      for (int i = 8; i < 128; i += 8)
#pragma unroll
        for (int j = 0; j < 8; ++j) r[j] = __fadd_rn(r[j], __fmul_rn(p[i + j], p[i + j]));
      float s = __fadd_rn(__fadd_rn(__fadd_rn(r[0], r[1]), __fadd_rn(r[2], r[3])),
                          __fadd_rn(__fadd_rn(r[4], r[5]), __fadd_rn(r[6], r[7])));
      tot = (h == 0) ? s : __fadd_rn(tot, s);
    }
    c2f[e] = tot;
  }
}

// ---------------------------------------------------------------- VQ: 4 rows/block (R15, validated)
__global__ __launch_bounds__(256) void vq_ref_k(const float* __restrict__ z,
                                                const float* __restrict__ cb,
                                                const float* __restrict__ c2f,
                                                float* __restrict__ zq_out,
                                                float* __restrict__ idx_out) {
  int n0 = blockIdx.x * 4;
  int t = threadIdx.x;
  __shared__ float f[4][256];
  __shared__ float dist[4][1024];
  __shared__ float rr[4][2][8];
  __shared__ float f2s[4];
  __shared__ int bestIdx[4];
  for (int e = t; e < 1024; e += 256) {
    int r = e >> 8, c = e & 255;
    f[r][c] = z[(size_t)(n0 + r) * 256 + c];
  }
  __syncthreads();
  if (t < 64) {
    int row = t >> 4, hh = (t >> 3) & 1, j = t & 7;
    const float* p = f[row] + hh * 128;
    float r = __fmul_rn(p[j], p[j]);
    for (int i = 8; i < 128; i += 8) r = __fadd_rn(r, __fmul_rn(p[i + j], p[i + j]));
    rr[row][hh][j] = r;
  }
  __syncthreads();
  if (t < 4) {
    float s0 = __fadd_rn(__fadd_rn(__fadd_rn(rr[t][0][0], rr[t][0][1]), __fadd_rn(rr[t][0][2], rr[t][0][3])),
                         __fadd_rn(__fadd_rn(rr[t][0][4], rr[t][0][5]), __fadd_rn(rr[t][0][6], rr[t][0][7])));
    float s1 = __fadd_rn(__fadd_rn(__fadd_rn(rr[t][1][0], rr[t][1][1]), __fadd_rn(rr[t][1][2], rr[t][1][3])),
                         __fadd_rn(__fadd_rn(rr[t][1][4], rr[t][1][5]), __fadd_rn(rr[t][1][6], rr[t][1][7])));
    f2s[t] = __fadd_rn(s0, s1);
  }
  __syncthreads();
  for (int e = t; e < 1024; e += 256) {
    const float4* cbe = reinterpret_cast<const float4*>(cb + (size_t)e * 256);
    double d0 = 0.0, d1 = 0.0, d2 = 0.0, d3 = 0.0;
    for (int d = 0; d < 64; ++d) {
      float4 c4 = cbe[d];
      float4 f0 = *reinterpret_cast<const float4*>(&f[0][d * 4]);
      float4 f1 = *reinterpret_cast<const float4*>(&f[1][d * 4]);
      float4 f2v = *reinterpret_cast<const float4*>(&f[2][d * 4]);
      float4 f3 = *reinterpret_cast<const float4*>(&f[3][d * 4]);
      d0 = fma((double)f0.x, (double)c4.x, d0); d0 = fma((double)f0.y, (double)c4.y, d0);
      d0 = fma((double)f0.z, (double)c4.z, d0); d0 = fma((double)f0.w, (double)c4.w, d0);
      d1 = fma((double)f1.x, (double)c4.x, d1); d1 = fma((double)f1.y, (double)c4.y, d1);
      d1 = fma((double)f1.z, (double)c4.z, d1); d1 = fma((double)f1.w, (double)c4.w, d1);
      d2 = fma((double)f2v.x, (double)c4.x, d2); d2 = fma((double)f2v.y, (double)c4.y, d2);
      d2 = fma((double)f2v.z, (double)c4.z, d2); d2 = fma((double)f2v.w, (double)c4.w, d2);
      d3 = fma((double)f3.x, (double)c4.x, d3); d3 = fma((double)f3.y, (double)c4.y, d3);
      d3 = fma((double)f3.z, (double)c4.z, d3); d3 = fma((double)f3.w, (double)c4.w, d3);
    }
    float c2e = c2f[e];
    dist[0][e] = __fsub_rn(__fadd_rn(f2s[0], c2e), __fmul_rn(2.f, (float)d0));
    dist[1][e] = __fsub_rn(__fadd_rn(f2s[1], c2e), __fmul_rn(2.f, (float)d1));
    dist[2][e] = __fsub_rn(__fadd_rn(f2s[2], c2e), __fmul_rn(2.f, (float)d2));
    dist[3][e] = __fsub_rn(__fadd_rn(f2s[3], c2e), __fmul_rn(2.f, (float)d3));
  }
  __syncthreads();
  {
    int row = t >> 6, l = t & 63;
    float bv = dist[row][l];
    int bi = l;
    for (int e = l + 64; e < 1024; e += 64) {
      float v = dist[row][e];
      if (v < bv) { bv = v; bi = e; }
    }
#pragma unroll
    for (int m = 1; m < 64; m <<= 1) {
      float ov = __shfl_xor(bv, m, 64);
      int oi = __shfl_xor(bi, m, 64);
      if (ov < bv || (ov == bv && oi < bi)) { bv = ov; bi = oi; }
    }
    if (l == 0) {
      bestIdx[row] = bi;
      idx_out[n0 + row] = (float)bi;
    }
  }
  __syncthreads();
#pragma unroll
  for (int r = 0; r < 4; ++r)
    zq_out[(size_t)(n0 + r) * 256 + t] = cb[(size_t)bestIdx[r] * 256 + t];
}

// ================================================================ host
extern "C" void kernel_launch(void* const* d_in, const int* in_sizes, int n_in,
                              void* d_out, int out_size, void* d_ws, size_t ws_size,
                              hipStream_t stream) {
  const float* x = (const float*)d_in[0];
  const float* w0 = (const float*)d_in[1];
  const float* b0 = (const float*)d_in[2];
  const float* a_c1w = (const float*)d_in[3];
  const float* a_c1b = (const float*)d_in[4];
  const float* a_c2w = (const float*)d_in[5];
  const float* a_c2b = (const float*)d_in[6];
  const float* a_scw = (const float*)d_in[7];
  const float* a_scb = (const float*)d_in[8];
  const float* b_c1w = (const float*)d_in[9];
  const float* b_c1b = (const float*)d_in[10];
  const float* b_c2w = (const float*)d_in[11];
  const float* b_c2b = (const float*)d_in[12];
  const float* b_scw = (const float*)d_in[13];
  const float* b_scb = (const float*)d_in[14];
  const float* ew = (const float*)d_in[15];
  const float* eb = (const float*)d_in[16];
  const float* cb = (const float*)d_in[17];
  const float* d0w = (const float*)d_in[18];
  const float* d0b = (const float*)d_in[19];
  const float* dt1w = (const float*)d_in[20];
  const float* dt1b = (const float*)d_in[21];
  const float* dt2w = (const float*)d_in[22];
  const float* dt2b = (const float*)d_in[23];
  const float* doww = (const float*)d_in[24];
  const float* dob = (const float*)d_in[25];

  // ws (floats): A 13.1M | B 6.55M | C 6.55M | c2f 1024  ~= 105 MB (unchanged)
  float* ws = (float*)d_ws;
  float* A = ws;
  float* Bf = ws + 13107200;
  float* Cf = ws + 19660800;
  float* c2f = ws + 26214400;
  // fp16-split A-frags (dead-region placements; liveness audited):
  _Float16* wh_ac1 = (_Float16*)(void*)Cf;              //   589,824 f16 = 294,912 f
  _Float16* wh_bc1 = (_Float16*)(void*)(Bf + 3300000);  // 2,359,296 f16 = 1,179,648 f
  _Float16* wh_ac2 = (_Float16*)(void*)(A + 6600000);   // 1,179,648 f16
  _Float16* wh_bc2 = (_Float16*)(void*)(A + 3300000);   // 4,718,592 f16
  __hip_bfloat16* wb_dt1 = (__hip_bfloat16*)(void*)A;
  __hip_bfloat16* wb_dt2 = (__hip_bfloat16*)(void*)(Bf + 3400000);

  float* outf = (float*)d_out;
  float* recon = outf;
  float* zq = outf + 409600;
  float* idxo = zq + 6553600;

  cbprep_np<<<1024, 256, 0, stream>>>(cb, c2f);

  for (int b = 0; b < 4; ++b) {
    const float* xb = x + (size_t)b * 102400;
    float* zqb = zq + (size_t)b * 1638400;
    float* idxb = idxo + (size_t)b * 6400;
    float* reconb = recon + (size_t)b * 102400;

    // encoder (all 3x3 layers via fp16-split MFMA)
    conv0_k<<<320, 320, 0, stream>>>(xb, w0, b0, A);                 // A = h0
    prep_w3h_k<<<2304, 256, 0, stream>>>(a_c1w, wh_ac1, 128, 256);   // Cf head (dead)
    conv3s2_mfma_k<<<dim3(10, 160, 4), 256, 0, stream>>>(
        A, wh_ac1, a_c1b, Bf, 128, 320, 320, 256, 160, 160);         // Bf = a_c1
    conv1x1_k<2, false><<<dim3(400, 4), 256, 0, stream>>>(
        A, a_scw, a_scb, Cf, 128, 320, 320, 256, 160, 160);          // Cf = a_sc (overwrites wh_ac1, now dead)
    prep_w3h_k<<<4608, 256, 0, stream>>>(a_c2w, wh_ac2, 256, 256);   // A+6.6M (h0 dead)
    conv3s1_mfma_k<<<dim3(10, 160, 4), 256, 0, stream>>>(
        Bf, wh_ac2, a_c2b, Cf, A, 256, 160, 256);                    // A = a_out
    prep_w3h_k<<<9216, 256, 0, stream>>>(b_c1w, wh_bc1, 256, 512);   // Bf+3.3M (a_c1 dead)
    conv3s2_mfma_k<<<dim3(5, 80, 8), 256, 0, stream>>>(
        A, wh_bc1, b_c1b, Bf, 256, 160, 160, 512, 80, 80);           // Bf = b_c1
    conv1x1_k<2, false><<<dim3(100, 8), 256, 0, stream>>>(
        A, b_scw, b_scb, Cf, 256, 160, 160, 512, 80, 80);            // Cf = b_sc
    prep_w3h_k<<<18432, 256, 0, stream>>>(b_c2w, wh_bc2, 512, 512);  // A+3.3M (a_out dead)
    conv3s1_mfma_k<<<dim3(5, 80, 8), 256, 0, stream>>>(
        Bf, wh_bc2, b_c2b, Cf, A, 512, 80, 512);                     // A = b_out
    conv1x1_k<1, false><<<dim3(100, 4), 256, 0, stream>>>(
        A, ew, eb, Cf, 512, 80, 80, 256, 80, 80);                    // Cf = z
    // VQ
    vq_ref_k<<<1600, 256, 0, stream>>>(Cf, cb, c2f, zqb, idxb);
    // decoder: bf16 MFMA ConvT (R14)
    prep_wb_k<<<8192, 256, 0, stream>>>(dt1w, wb_dt1, 512, 256);
    prep_wb_k<<<2048, 256, 0, stream>>>(dt2w, wb_dt2, 256, 128);
    conv1x1_k<1, true><<<dim3(100, 8), 256, 0, stream>>>(
        zqb, d0w, d0b, Bf, 256, 80, 80, 512, 80, 80);
    convt_mfma_k<<<dim3(5, 160, 4), 256, 0, stream>>>(
        Bf, wb_dt1, dt1b, Cf, 512, 80, 80, 256, 160, 160);
    convt_mfma_k<<<dim3(10, 320, 2), 256, 0, stream>>>(
        Cf, wb_dt2, dt2b, A, 256, 160, 160, 128, 320, 320);
    dow_k<<<320, 320, 0, stream>>>(A, doww, dob, reconb);
  }
}